// Round 7
// baseline (410.654 us; speedup 1.0000x reference)
//
#include <hip/hip_runtime.h>
#include <hip/hip_bf16.h>
#include <cmath>

// GAT layer.  B=4, N=2047 (+1 prior node), I=256, O=128, H=4.  bf16 in/out
// (dtype runtime-detected; R6 confirmed bf16).  Attention factorization:
// exp(leakyrelu(si+sj)) = e^si e^sj (sj>=-si) | e^.2si e^.2sj (else);
// bucket j by s_dst (256 bins, counting sort), per-bin channel sums,
// prefix/suffix over bins, boundary bin tested element-wise. O(N^2*O)->O(N*O).
// R7: k1/k2 register-blocked GEMMs (R6 showed LDS-issue-bound: 9 LDS reads
// per 8 FMA, VALUBusy 27%); k3d heads parallelized across 512-thr block.

#define B_ 4
#define N_ 2047
#define N1 2048
#define I_ 256
#define O_ 128
#define H_ 4
#define NBINS 256
#define STR 132
#define SLOPEC 0.2f

typedef unsigned short u16;
typedef unsigned char u8;

__device__ __forceinline__ float bf2f(u16 v){
  union { unsigned u; float f; } x; x.u = ((unsigned)v) << 16; return x.f;
}
__device__ __forceinline__ u16 f2bf(float f){
  union { float f; unsigned u; } x; x.f = f;
  unsigned u = x.u;
  return (u16)((u + 0x7FFFu + ((u >> 16) & 1u)) >> 16);
}
__device__ __forceinline__ float ldv(const void* p, int bf, size_t i){
  if (bf) return bf2f(reinterpret_cast<const u16*>(p)[i]);
  return reinterpret_cast<const float*>(p)[i];
}
// load 8 consecutive elements (i must be 8-elem aligned); wave-uniform bf
__device__ __forceinline__ void ld8(const void* p, int bf, size_t i, float* o){
  if (bf){
    uint4 v = *reinterpret_cast<const uint4*>(reinterpret_cast<const u16*>(p) + i);
    o[0]=bf2f((u16)(v.x&0xFFFF)); o[1]=bf2f((u16)(v.x>>16));
    o[2]=bf2f((u16)(v.y&0xFFFF)); o[3]=bf2f((u16)(v.y>>16));
    o[4]=bf2f((u16)(v.z&0xFFFF)); o[5]=bf2f((u16)(v.z>>16));
    o[6]=bf2f((u16)(v.w&0xFFFF)); o[7]=bf2f((u16)(v.w>>16));
  } else {
    const float4* q = reinterpret_cast<const float4*>(reinterpret_cast<const float*>(p) + i);
    float4 a = q[0], b = q[1];
    o[0]=a.x; o[1]=a.y; o[2]=a.z; o[3]=a.w;
    o[4]=b.x; o[5]=b.y; o[6]=b.z; o[7]=b.w;
  }
}
__device__ __forceinline__ float clS(float v){ return fminf(30.f, fmaxf(-30.f, v)); }
__device__ __forceinline__ float clH(float v){ return fminf(1e4f, fmaxf(-1e4f, v)); }
__device__ __forceinline__ int binOf(float v, float lo, float inv){
  int c = (int)((v - lo) * inv);
  c = c < 0 ? 0 : c;
  c = c > NBINS - 1 ? NBINS - 1 : c;
  return c;
}
__device__ __forceinline__ int rdmask(const u8* m, int mode, int idx){
  return mode ? (m[idx] != 0) : (((const int*)m)[idx] != 0);
}

// flags: [0]=mask-is-u8, [1]=x bf16, [2]=prior, [3]=Wlin, [4]=w_head,
//        [5]=a_src, [6]=a_dst.  Also zeroes colsum.   (unchanged from R6)
__global__ __launch_bounds__(256) void k0_detect(const u8* __restrict__ mask,
                                                 const void* x, const void* prior,
                                                 const void* Wlin, const void* wh,
                                                 const void* asr, const void* ads,
                                                 int* __restrict__ flags,
                                                 float* __restrict__ colsum){
  __shared__ int c[8];
  const int t = threadIdx.x;
  for (int i = t; i < B_ * H_ * O_; i += 256) colsum[i] = 0.f;
  if (t < 8) c[t] = 0;
  __syncthreads();
  int local = 0;
  for (int i = t; i < B_ * N1; i += 256)
    if ((i & 3) && mask[i]) local = 1;
  if (local) atomicOr(&c[0], 1);
  const void* ptrs[6] = {x, prior, Wlin, wh, asr, ads};
  const int   lens[6] = {4096, 512, 4096, 4096, 512, 512};
  for (int k = 0; k < 6; k++){
    const u16* p = (const u16*)ptrs[k];
    int g = 0;
    for (int i = t; i < lens[k]; i += 256){
      int e = (p[i] >> 7) & 0xFF;
      if (e >= 0xC0) g++;
    }
    if (g) atomicAdd(&c[k + 1], g);
  }
  __syncthreads();
  if (t == 0) flags[0] = c[0];
  else if (t <= 6) flags[t] = (c[t] < 4) ? 1 : 0;
}

// ---- K1: hp[b,n,o] = sum_i x[b,n,i]*Wlin[o,i]; row 2047 = prior ----
// 64 rows x 64 cols per block; 256 thr; 4x4 micro-tile; K-tile 32.
__global__ __launch_bounds__(256) void k1_hp(const void* __restrict__ x,
                                             const void* __restrict__ prior,
                                             const void* __restrict__ Wlin,
                                             const int* __restrict__ flags,
                                             float* __restrict__ hp){
  __shared__ __align__(16) float xs[64][36];    // rows x ktile(32)+pad
  __shared__ __align__(16) float wsT[32][68];   // ktile x cols(64)+pad
  const int fx = flags[1], fpf = flags[2], fw = flags[3];
  const int colh = blockIdx.x & 1;
  const int tile = (blockIdx.x >> 1) & 31;
  const int b    = blockIdx.x >> 6;
  const int n0   = tile * 64;
  const int o0   = colh * 64;
  const int t    = threadIdx.x;
  const int rg = t >> 4, cg = t & 15;           // 16x16 thread grid
  float acc[4][4];
#pragma unroll
  for (int i = 0; i < 4; i++)
#pragma unroll
    for (int j = 0; j < 4; j++) acc[i][j] = 0.f;

  const int srow = t >> 2, sc = (t & 3) * 8;    // xs staging map
  const int wo = t & 63, wk0 = (t >> 6) * 8;    // wsT staging map
  for (int kt = 0; kt < I_; kt += 32){
    // stage x rows
    {
      float v[8];
      const int n = n0 + srow;
      if (n < N_) ld8(x, fx, ((size_t)b * N_ + n) * I_ + kt + sc, v);
      else { for (int m = 0; m < 8; m++) v[m] = 0.f; }
      float4* d = reinterpret_cast<float4*>(&xs[srow][sc]);
      d[0] = make_float4(v[0], v[1], v[2], v[3]);
      d[1] = make_float4(v[4], v[5], v[6], v[7]);
    }
    // stage Wlin^T (coalesced row reads, transposed scalar LDS writes)
    {
      float v[8];
      ld8(Wlin, fw, ((size_t)(o0 + wo)) * I_ + kt + wk0, v);
#pragma unroll
      for (int m = 0; m < 8; m++) wsT[wk0 + m][wo] = v[m];
    }
    __syncthreads();
#pragma unroll 8
    for (int kk = 0; kk < 32; kk++){
      const float a0 = xs[rg * 4 + 0][kk];
      const float a1 = xs[rg * 4 + 1][kk];
      const float a2 = xs[rg * 4 + 2][kk];
      const float a3 = xs[rg * 4 + 3][kk];
      const float4 bv = *reinterpret_cast<const float4*>(&wsT[kk][cg * 4]);
      acc[0][0] += a0 * bv.x; acc[0][1] += a0 * bv.y; acc[0][2] += a0 * bv.z; acc[0][3] += a0 * bv.w;
      acc[1][0] += a1 * bv.x; acc[1][1] += a1 * bv.y; acc[1][2] += a1 * bv.z; acc[1][3] += a1 * bv.w;
      acc[2][0] += a2 * bv.x; acc[2][1] += a2 * bv.y; acc[2][2] += a2 * bv.z; acc[2][3] += a2 * bv.w;
      acc[3][0] += a3 * bv.x; acc[3][1] += a3 * bv.y; acc[3][2] += a3 * bv.z; acc[3][3] += a3 * bv.w;
    }
    __syncthreads();
  }
  const int col0 = o0 + cg * 4;
#pragma unroll
  for (int i = 0; i < 4; i++){
    const int n = n0 + rg * 4 + i;
    float4 v;
    if (n == N_){
      v = make_float4(ldv(prior, fpf, b * O_ + col0),
                      ldv(prior, fpf, b * O_ + col0 + 1),
                      ldv(prior, fpf, b * O_ + col0 + 2),
                      ldv(prior, fpf, b * O_ + col0 + 3));
    } else {
      v = make_float4(acc[i][0], acc[i][1], acc[i][2], acc[i][3]);
    }
    *reinterpret_cast<float4*>(&hp[((size_t)b * N1 + n) * O_ + col0]) = v;
  }
}

// ---- K2: hph = hp @ w_head[h]; tanh; s_src/s_dst; colsum ----
// 64 rows x 128 cols per block; 256 thr; 4x8 micro-tile; K-tile 32.
__global__ __launch_bounds__(256) void k2_heads(const float* __restrict__ hp,
                                                const void* __restrict__ w_head,
                                                const void* __restrict__ a_src,
                                                const void* __restrict__ a_dst,
                                                const int* __restrict__ flags,
                                                float* __restrict__ hph,
                                                float* __restrict__ s_src,
                                                float* __restrict__ s_dst,
                                                float* __restrict__ colsum){
  __shared__ __align__(16) float hs[64][132];   // rows x K(128)+pad  (33.8 KB)
  __shared__ __align__(16) float ws[32][132];   // ktile x cols(128)+pad (16.9 KB)
  const int fw = flags[4], fas = flags[5], fad = flags[6];
  const int tile = blockIdx.x & 31;
  const int h    = (blockIdx.x >> 5) & 3;
  const int b    = blockIdx.x >> 7;
  const int bh   = b * H_ + h;
  const int n0   = tile * 64;
  const int t    = threadIdx.x;
  const int rg = t >> 4, cg = t & 15;           // 16 row-groups x 16 col-groups
  // stage hs once (hp is fp32)
  {
    const int row = t >> 2, c0 = (t & 3) * 32;
    const float4* src = reinterpret_cast<const float4*>(&hp[((size_t)b * N1 + n0 + row) * O_ + c0]);
    float4* dst = reinterpret_cast<float4*>(&hs[row][c0]);
#pragma unroll
    for (int m = 0; m < 8; m++) dst[m] = src[m];
  }
  float acc[4][8];
#pragma unroll
  for (int i = 0; i < 4; i++)
#pragma unroll
    for (int j = 0; j < 8; j++) acc[i][j] = 0.f;

  const int skk = t >> 3, scb = (t & 7) * 16;   // ws staging map
  for (int kt = 0; kt < O_; kt += 32){
    // stage w_head K-tile
    {
      float v[16];
      const size_t base = (size_t)h * O_ * O_ + (size_t)(kt + skk) * O_ + scb;
      ld8(w_head, fw, base, v);
      ld8(w_head, fw, base + 8, v + 8);
      float4* d = reinterpret_cast<float4*>(&ws[skk][scb]);
      d[0] = make_float4(v[0], v[1], v[2], v[3]);
      d[1] = make_float4(v[4], v[5], v[6], v[7]);
      d[2] = make_float4(v[8], v[9], v[10], v[11]);
      d[3] = make_float4(v[12], v[13], v[14], v[15]);
    }
    __syncthreads();
#pragma unroll 8
    for (int kk = 0; kk < 32; kk++){
      const int k = kt + kk;
      const float a0 = hs[rg * 4 + 0][k];
      const float a1 = hs[rg * 4 + 1][k];
      const float a2 = hs[rg * 4 + 2][k];
      const float a3 = hs[rg * 4 + 3][k];
      const float4 b0 = *reinterpret_cast<const float4*>(&ws[kk][cg * 8]);
      const float4 b1 = *reinterpret_cast<const float4*>(&ws[kk][cg * 8 + 4]);
      acc[0][0] += a0 * b0.x; acc[0][1] += a0 * b0.y; acc[0][2] += a0 * b0.z; acc[0][3] += a0 * b0.w;
      acc[0][4] += a0 * b1.x; acc[0][5] += a0 * b1.y; acc[0][6] += a0 * b1.z; acc[0][7] += a0 * b1.w;
      acc[1][0] += a1 * b0.x; acc[1][1] += a1 * b0.y; acc[1][2] += a1 * b0.z; acc[1][3] += a1 * b0.w;
      acc[1][4] += a1 * b1.x; acc[1][5] += a1 * b1.y; acc[1][6] += a1 * b1.z; acc[1][7] += a1 * b1.w;
      acc[2][0] += a2 * b0.x; acc[2][1] += a2 * b0.y; acc[2][2] += a2 * b0.z; acc[2][3] += a2 * b0.w;
      acc[2][4] += a2 * b1.x; acc[2][5] += a2 * b1.y; acc[2][6] += a2 * b1.z; acc[2][7] += a2 * b1.w;
      acc[3][0] += a3 * b0.x; acc[3][1] += a3 * b0.y; acc[3][2] += a3 * b0.z; acc[3][3] += a3 * b0.w;
      acc[3][4] += a3 * b1.x; acc[3][5] += a3 * b1.y; acc[3][6] += a3 * b1.z; acc[3][7] += a3 * b1.w;
    }
    __syncthreads();
  }
  // epilogue
  const int c0 = cg * 8;
  float asv[8], adv[8];
#pragma unroll
  for (int j = 0; j < 8; j++){
    asv[j] = ldv(a_src, fas, h * O_ + c0 + j);
    adv[j] = ldv(a_dst, fad, h * O_ + c0 + j);
  }
  float csum[8];
#pragma unroll
  for (int j = 0; j < 8; j++) csum[j] = 0.f;
#pragma unroll
  for (int i = 0; i < 4; i++){
    const int n = n0 + rg * 4 + i;
    float v[8], cs = 0.f, cd = 0.f;
#pragma unroll
    for (int j = 0; j < 8; j++){
      v[j] = clH(acc[i][j]);
      csum[j] += v[j];
      const float tv = tanhf(v[j]);
      cs += tv * asv[j];
      cd += tv * adv[j];
    }
    float4* dst = reinterpret_cast<float4*>(&hph[((size_t)bh * N1 + n) * O_ + c0]);
    dst[0] = make_float4(v[0], v[1], v[2], v[3]);
    dst[1] = make_float4(v[4], v[5], v[6], v[7]);
    // reduce cs/cd across the 16 col-groups (16 consecutive lanes)
#pragma unroll
    for (int m = 8; m > 0; m >>= 1){
      cs += __shfl_xor(cs, m);
      cd += __shfl_xor(cd, m);
    }
    if (cg == 0){
      s_src[(size_t)bh * N1 + n] = cs;
      s_dst[(size_t)bh * N1 + n] = cd;
    }
  }
#pragma unroll
  for (int j = 0; j < 8; j++)
    atomicAdd(&colsum[bh * O_ + c0 + j], csum[j]);
}

// ---- K2b: min/max of s_dst over unmasked j -> bin range (unchanged) ----
__global__ __launch_bounds__(256) void k2b_range(const float* __restrict__ s_dst,
                                                 const u8* __restrict__ mask,
                                                 const int* __restrict__ flags,
                                                 float* __restrict__ sdlo,
                                                 float* __restrict__ sdinv){
  __shared__ float smn[4], smx[4];
  const int bh = blockIdx.x, b = bh / H_, t = threadIdx.x;
  const int md = flags[0];
  float mn = 3e38f, mx = -3e38f;
  for (int j = t; j < N1; j += 256){
    if (!rdmask(mask, md, b * N1 + j)){
      float v = clS(s_dst[(size_t)bh * N1 + j]);
      mn = fminf(mn, v); mx = fmaxf(mx, v);
    }
  }
#pragma unroll
  for (int sft = 32; sft > 0; sft >>= 1){
    mn = fminf(mn, __shfl_down(mn, sft));
    mx = fmaxf(mx, __shfl_down(mx, sft));
  }
  if ((t & 63) == 0){ smn[t >> 6] = mn; smx[t >> 6] = mx; }
  __syncthreads();
  if (t == 0){
    mn = fminf(fminf(smn[0], smn[1]), fminf(smn[2], smn[3]));
    mx = fmaxf(fmaxf(smx[0], smx[1]), fmaxf(smx[2], smx[3]));
    float range = mx - mn;
    if (!(range > 1e-30f)) range = 1.f;
    sdlo[bh]  = mn;
    sdinv[bh] = (float)NBINS / range;
  }
}

// ---- K3a: counting sort of unmasked j by bin (unchanged) ----
__global__ __launch_bounds__(256) void k3a_bucket(const float* __restrict__ s_dst,
                                                  const u8* __restrict__ mask,
                                                  const int* __restrict__ flags,
                                                  const float* __restrict__ sdlo,
                                                  const float* __restrict__ sdinv,
                                                  int* __restrict__ binStart,
                                                  int* __restrict__ order){
  __shared__ int cnt[NBINS];
  __shared__ int part[256];
  __shared__ int offs[NBINS];
  const int bh = blockIdx.x, b = bh / H_, t = threadIdx.x;
  const int md = flags[0];
  const float lo = sdlo[bh], inv = sdinv[bh];
  cnt[t] = 0;
  __syncthreads();
  for (int j = t; j < N1; j += 256){
    if (!rdmask(mask, md, b * N1 + j))
      atomicAdd(&cnt[binOf(clS(s_dst[(size_t)bh * N1 + j]), lo, inv)], 1);
  }
  __syncthreads();
  const int mysum = cnt[t];
  part[t] = mysum;
  __syncthreads();
  for (int off = 1; off < 256; off <<= 1){
    int v = (t >= off) ? part[t - off] : 0;
    __syncthreads();
    part[t] += v;
    __syncthreads();
  }
  const int excl = part[t] - mysum;
  offs[t] = excl;
  binStart[bh * (NBINS + 1) + t] = excl;
  if (t == 255) binStart[bh * (NBINS + 1) + NBINS] = part[255];
  __syncthreads();
  for (int j = t; j < N1; j += 256){
    if (!rdmask(mask, md, b * N1 + j)){
      int bin = binOf(clS(s_dst[(size_t)bh * N1 + j]), lo, inv);
      int pos = atomicAdd(&offs[bin], 1);
      order[(size_t)bh * N1 + pos] = j;
    }
  }
}

// ---- K3b: per-bin sums (channel 128 = ones) (unchanged) ----
__global__ __launch_bounds__(192) void k3b_binsum(const float* __restrict__ hph,
                                                  const float* __restrict__ s_dst,
                                                  const int* __restrict__ binStart,
                                                  const int* __restrict__ order,
                                                  float* __restrict__ binPos,
                                                  float* __restrict__ binNeg){
  const int gb = blockIdx.x;
  const int bh = gb / NBINS, bin = gb % NBINS;
  const int t = threadIdx.x;
  const int s = binStart[bh * (NBINS + 1) + bin];
  const int e = binStart[bh * (NBINS + 1) + bin + 1];
  float ap = 0.f, an = 0.f;
  for (int m = s; m < e; m++){
    const int j = order[(size_t)bh * N1 + m];
    const float sdj = clS(s_dst[(size_t)bh * N1 + j]);
    const float fp = __expf(sdj), fn = __expf(SLOPEC * sdj);
    const float v = (t < O_) ? hph[((size_t)bh * N1 + j) * O_ + t] : 1.f;
    ap += fp * v; an += fn * v;
  }
  if (t <= O_){
    const size_t basei = ((size_t)bh * NBINS + bin) * STR;
    binPos[basei + t] = ap;
    binNeg[basei + t] = an;
  }
}

// ---- K3c: prefix/suffix over bins (unchanged) ----
__global__ __launch_bounds__(64) void k3c_prefix(const float* __restrict__ binPos,
                                                 const float* __restrict__ binNeg,
                                                 float* __restrict__ sufPos,
                                                 float* __restrict__ preNeg){
  const int idx = blockIdx.x * 64 + threadIdx.x;
  if (idx >= 2 * B_ * H_ * 129) return;
  const int ch  = idx % 129;
  const int g   = idx / 129;
  const int bh  = g % (B_ * H_);
  const int arr = g / (B_ * H_);
  if (arr == 0){
    float acc = 0.f;
    for (int r = 0; r < NBINS; r++){
      preNeg[((size_t)bh * (NBINS + 1) + r) * STR + ch] = acc;
      acc += binNeg[((size_t)bh * NBINS + r) * STR + ch];
    }
    preNeg[((size_t)bh * (NBINS + 1) + NBINS) * STR + ch] = acc;
  } else {
    float acc = 0.f;
    sufPos[((size_t)bh * (NBINS + 1) + NBINS) * STR + ch] = 0.f;
    for (int r = NBINS - 1; r >= 0; r--){
      acc += binPos[((size_t)bh * NBINS + r) * STR + ch];
      sufPos[((size_t)bh * (NBINS + 1) + r) * STR + ch] = acc;
    }
  }
}

// ---- K3d: output rows; heads parallel across 512-thr block ----
__global__ __launch_bounds__(512) void k3d_out(const float* __restrict__ hph,
                                               const float* __restrict__ s_src,
                                               const float* __restrict__ s_dst,
                                               const u8* __restrict__ mask,
                                               const int* __restrict__ flags,
                                               const float* __restrict__ sdlo,
                                               const float* __restrict__ sdinv,
                                               const int* __restrict__ binStart,
                                               const int* __restrict__ order,
                                               const float* __restrict__ sufPos,
                                               const float* __restrict__ preNeg,
                                               const float* __restrict__ colsum,
                                               const void* __restrict__ bias,
                                               void* __restrict__ outp){
  __shared__ float part[4][O_];
  const int blk = blockIdx.x;
  const int b = blk / N1, i = blk % N1;
  const int t = threadIdx.x;
  const int h = t >> 7, o = t & 127;
  const int md = flags[0], fo = flags[1];
  const bool mrow = rdmask(mask, md, b * N1 + i) != 0;
  const int bh = b * H_ + h;
  const int U = binStart[bh * (NBINS + 1) + NBINS];
  float contrib;
  if (mrow || U == 0){
    contrib = colsum[bh * O_ + o] * (1.f / N1);
  } else {
    const float si = clS(s_src[(size_t)bh * N1 + i]);
    const float tthr = -si;
    const int c = binOf(tthr, sdlo[bh], sdinv[bh]);
    const size_t rowp = ((size_t)bh * (NBINS + 1) + c + 1) * STR;
    const size_t rown = ((size_t)bh * (NBINS + 1) + c) * STR;
    float posV = sufPos[rowp + o], posS = sufPos[rowp + O_];
    float negV = preNeg[rown + o], negS = preNeg[rown + O_];
    const int s0 = binStart[bh * (NBINS + 1) + c];
    const int e0 = binStart[bh * (NBINS + 1) + c + 1];
    for (int m = s0; m < e0; m++){
      const int j = order[(size_t)bh * N1 + m];
      const float sdj = clS(s_dst[(size_t)bh * N1 + j]);
      const float hv = hph[((size_t)bh * N1 + j) * O_ + o];
      if (sdj >= tthr){ const float fp = __expf(sdj);          posV += fp * hv; posS += fp; }
      else            { const float fn = __expf(SLOPEC * sdj); negV += fn * hv; negS += fn; }
    }
    const float esi = __expf(si), esi2 = __expf(SLOPEC * si);
    const float den = fmaxf(esi * posS + esi2 * negS, 1e-35f);
    contrib = (esi * posV + esi2 * negV) / den;
  }
  part[h][o] = contrib;
  __syncthreads();
  if (t < O_){
    const float sum = part[0][t] + part[1][t] + part[2][t] + part[3][t];
    const float v = 0.25f * sum + ldv(bias, fo, t);
    const size_t oidx = ((size_t)b * N1 + i) * O_ + t;
    if (fo) ((u16*)outp)[oidx] = f2bf(v);
    else    ((float*)outp)[oidx] = v;
  }
}

extern "C" void kernel_launch(void* const* d_in, const int* in_sizes, int n_in,
                              void* d_out, int out_size, void* d_ws, size_t ws_size,
                              hipStream_t stream){
  const void* x      = d_in[0];
  const void* prior  = d_in[1];
  const u8*   mask   = (const u8*)d_in[2];
  const void* Wlin   = d_in[3];
  const void* w_head = d_in[4];
  const void* a_src  = d_in[5];
  const void* a_dst  = d_in[6];
  const void* bias   = d_in[7];

  char* basep = (char*)d_ws;
  size_t off = 0;
  auto alloc = [&](size_t bytes) -> void* {
    off = (off + 255) & ~(size_t)255;
    void* p = basep + off;
    off += bytes;
    return p;
  };
  int*   flags    = (int*)alloc(32);
  float* hp       = (float*)alloc((size_t)B_ * N1 * O_ * 4);
  float* hph      = (float*)alloc((size_t)B_ * H_ * N1 * O_ * 4);
  float* s_src    = (float*)alloc((size_t)B_ * H_ * N1 * 4);
  float* s_dst    = (float*)alloc((size_t)B_ * H_ * N1 * 4);
  float* sdlo     = (float*)alloc(B_ * H_ * 4);
  float* sdinv    = (float*)alloc(B_ * H_ * 4);
  float* colsum   = (float*)alloc((size_t)B_ * H_ * O_ * 4);
  int*   binStart = (int*)alloc((size_t)B_ * H_ * (NBINS + 1) * 4);
  int*   order    = (int*)alloc((size_t)B_ * H_ * N1 * 4);
  float* binPos   = (float*)alloc((size_t)B_ * H_ * NBINS * STR * 4);
  float* binNeg   = (float*)alloc((size_t)B_ * H_ * NBINS * STR * 4);
  float* sufPos   = (float*)alloc((size_t)B_ * H_ * (NBINS + 1) * STR * 4);
  float* preNeg   = (float*)alloc((size_t)B_ * H_ * (NBINS + 1) * STR * 4);
  (void)in_sizes; (void)n_in; (void)out_size; (void)ws_size;

  hipLaunchKernelGGL(k0_detect,  dim3(1),                dim3(256), 0, stream, mask, x, prior, Wlin, w_head, a_src, a_dst, flags, colsum);
  hipLaunchKernelGGL(k1_hp,      dim3(B_ * 32 * 2),      dim3(256), 0, stream, x, prior, Wlin, flags, hp);
  hipLaunchKernelGGL(k2_heads,   dim3(B_ * H_ * 32),     dim3(256), 0, stream, hp, w_head, a_src, a_dst, flags, hph, s_src, s_dst, colsum);
  hipLaunchKernelGGL(k2b_range,  dim3(B_ * H_),          dim3(256), 0, stream, s_dst, mask, flags, sdlo, sdinv);
  hipLaunchKernelGGL(k3a_bucket, dim3(B_ * H_),          dim3(256), 0, stream, s_dst, mask, flags, sdlo, sdinv, binStart, order);
  hipLaunchKernelGGL(k3b_binsum, dim3(B_ * H_ * NBINS),  dim3(192), 0, stream, hph, s_dst, binStart, order, binPos, binNeg);
  hipLaunchKernelGGL(k3c_prefix, dim3((2 * B_ * H_ * 129 + 63) / 64), dim3(64), 0, stream, binPos, binNeg, sufPos, preNeg);
  hipLaunchKernelGGL(k3d_out,    dim3(B_ * N1),          dim3(512), 0, stream, hph, s_src, s_dst, mask, flags, sdlo, sdinv, binStart, order, sufPos, preNeg, colsum, bias, d_out);
}

// Round 8
// 252.028 us; speedup vs baseline: 1.6294x; 1.6294x over previous
//
#include <hip/hip_runtime.h>
#include <hip/hip_bf16.h>
#include <cmath>

// GAT layer.  B=4, N=2047 (+1 prior), I=256, O=128, H=4.  bf16 in/out.
// Attention factorization: exp(leakyrelu(si+sj)) = e^si e^sj (sj>=-si) else
// e^.2si e^.2sj; bucket j by s_dst (256 bins), per-bin channel sums,
// prefix/suffix over bins, boundary bin element-wise.  O(N^2*O)->O(N*O).
// R8: k1/k2 via MFMA 16x16x32 bf16 (R7 showed VALU GEMMs are occupancy x
// latency bound, not FMA bound).  w_head pre-transposed to global (ktr);
// hp stored bf16; colsum in its own kernel (k2c).

#define B_ 4
#define N_ 2047
#define N1 2048
#define I_ 256
#define O_ 128
#define H_ 4
#define NBINS 256
#define STR 132
#define SLOPEC 0.2f
#define HS_STR 136   // u16 stride, 16B-aligned, for 128-col LDS tiles
#define XS_STR 72    // u16 stride for 64-col K-tiles

typedef unsigned short u16;
typedef unsigned char u8;
typedef short bf16x8 __attribute__((ext_vector_type(8)));
typedef float f32x4 __attribute__((ext_vector_type(4)));
#define MFMA16(a,b,c) __builtin_amdgcn_mfma_f32_16x16x32_bf16(a,b,c,0,0,0)

__device__ __forceinline__ float bf2f(u16 v){
  union { unsigned u; float f; } x; x.u = ((unsigned)v) << 16; return x.f;
}
__device__ __forceinline__ u16 f2bf(float f){
  union { float f; unsigned u; } x; x.f = f;
  unsigned u = x.u;
  return (u16)((u + 0x7FFFu + ((u >> 16) & 1u)) >> 16);
}
__device__ __forceinline__ float ldv(const void* p, int bf, size_t i){
  if (bf) return bf2f(reinterpret_cast<const u16*>(p)[i]);
  return reinterpret_cast<const float*>(p)[i];
}
__device__ __forceinline__ void ld8(const void* p, int bf, size_t i, float* o){
  if (bf){
    uint4 v = *reinterpret_cast<const uint4*>(reinterpret_cast<const u16*>(p) + i);
    o[0]=bf2f((u16)(v.x&0xFFFF)); o[1]=bf2f((u16)(v.x>>16));
    o[2]=bf2f((u16)(v.y&0xFFFF)); o[3]=bf2f((u16)(v.y>>16));
    o[4]=bf2f((u16)(v.z&0xFFFF)); o[5]=bf2f((u16)(v.z>>16));
    o[6]=bf2f((u16)(v.w&0xFFFF)); o[7]=bf2f((u16)(v.w>>16));
  } else {
    const float4* q = reinterpret_cast<const float4*>(reinterpret_cast<const float*>(p) + i);
    float4 a = q[0], b = q[1];
    o[0]=a.x; o[1]=a.y; o[2]=a.z; o[3]=a.w;
    o[4]=b.x; o[5]=b.y; o[6]=b.z; o[7]=b.w;
  }
}
// stage 8 input elems (bf16 passthrough or fp32->bf16) into 16B-aligned LDS
__device__ __forceinline__ void st8bf(u16* dst, const void* src, int bf, size_t i){
  if (bf){
    *reinterpret_cast<uint4*>(dst) =
      *reinterpret_cast<const uint4*>(reinterpret_cast<const u16*>(src) + i);
  } else {
    float v[8]; ld8(src, 0, i, v);
    u16 tmp[8];
#pragma unroll
    for (int m = 0; m < 8; m++) tmp[m] = f2bf(v[m]);
    *reinterpret_cast<uint4*>(dst) = *reinterpret_cast<uint4*>(tmp);
  }
}
__device__ __forceinline__ float clS(float v){ return fminf(30.f, fmaxf(-30.f, v)); }
__device__ __forceinline__ float clH(float v){ return fminf(1e4f, fmaxf(-1e4f, v)); }
__device__ __forceinline__ int binOf(float v, float lo, float inv){
  int c = (int)((v - lo) * inv);
  c = c < 0 ? 0 : c;
  c = c > NBINS - 1 ? NBINS - 1 : c;
  return c;
}
__device__ __forceinline__ int rdmask(const u8* m, int mode, int idx){
  return mode ? (m[idx] != 0) : (((const int*)m)[idx] != 0);
}

// flags: [0]=mask-is-u8, [1]=x bf16, [2]=prior, [3]=Wlin, [4]=w_head,
//        [5]=a_src, [6]=a_dst.  Also zeroes colsum.
__global__ __launch_bounds__(256) void k0_detect(const u8* __restrict__ mask,
                                                 const void* x, const void* prior,
                                                 const void* Wlin, const void* wh,
                                                 const void* asr, const void* ads,
                                                 int* __restrict__ flags,
                                                 float* __restrict__ colsum){
  __shared__ int c[8];
  const int t = threadIdx.x;
  for (int i = t; i < B_ * H_ * O_; i += 256) colsum[i] = 0.f;
  if (t < 8) c[t] = 0;
  __syncthreads();
  int local = 0;
  for (int i = t; i < B_ * N1; i += 256)
    if ((i & 3) && mask[i]) local = 1;
  if (local) atomicOr(&c[0], 1);
  const void* ptrs[6] = {x, prior, Wlin, wh, asr, ads};
  const int   lens[6] = {4096, 512, 4096, 4096, 512, 512};
  for (int k = 0; k < 6; k++){
    const u16* p = (const u16*)ptrs[k];
    int g = 0;
    for (int i = t; i < lens[k]; i += 256){
      int e = (p[i] >> 7) & 0xFF;
      if (e >= 0xC0) g++;
    }
    if (g) atomicAdd(&c[k + 1], g);
  }
  __syncthreads();
  if (t == 0) flags[0] = c[0];
  else if (t <= 6) flags[t] = (c[t] < 4) ? 1 : 0;
}

// ---- ktr: wT[h][p][o] = bf16(w_head[h][o][p]) ----
__global__ __launch_bounds__(256) void ktr(const void* __restrict__ w_head,
                                           const int* __restrict__ flags,
                                           u16* __restrict__ wT){
  const int fw = flags[4];
  const int idx = blockIdx.x * 256 + threadIdx.x;   // 65536 total
  const int h = idx >> 14, rem = idx & 16383, p = rem >> 7, o = rem & 127;
  wT[idx] = f2bf(ldv(w_head, fw, ((size_t)h * O_ + o) * O_ + p));
}

// ---- K1 (MFMA): hpb[b][n][o] = bf16( sum_i x[b,n,i]*Wlin[o,i] ); row 2047=prior
// 32 rows x 128 cols per block; 128 thr (2 waves, 16-row strips); K-tile 64.
__global__ __launch_bounds__(128) void k1_hp(const void* __restrict__ x,
                                             const void* __restrict__ prior,
                                             const void* __restrict__ Wlin,
                                             const int* __restrict__ flags,
                                             u16* __restrict__ hpb){
  __shared__ __align__(16) u16 xs[32 * XS_STR];    // 4.6 KB
  __shared__ __align__(16) u16 wl[128 * XS_STR];   // 18.4 KB
  const int fx = flags[1], fpf = flags[2], fw = flags[3];
  const int tile = blockIdx.x & 63;
  const int b    = blockIdx.x >> 6;
  const int n0   = tile * 32;
  const int t = threadIdx.x;
  const int w = t >> 6, lane = t & 63, m16 = lane & 15, q = lane >> 4;
  f32x4 acc[8];
#pragma unroll
  for (int nt = 0; nt < 8; nt++) acc[nt] = (f32x4){0.f, 0.f, 0.f, 0.f};
  for (int kt = 0; kt < I_; kt += 64){
    if (kt) __syncthreads();
    // stage x rows (32 x 8 chunks = 256 slots)
#pragma unroll
    for (int it = 0; it < 2; it++){
      const int slot = t + it * 128, row = slot >> 3, ch = slot & 7;
      const int n = n0 + row;
      if (n < N_) st8bf(&xs[row * XS_STR + ch * 8], x, fx, ((size_t)b * N_ + n) * I_ + kt + ch * 8);
      else { uint4 z = make_uint4(0,0,0,0); *reinterpret_cast<uint4*>(&xs[row * XS_STR + ch * 8]) = z; }
    }
    // stage Wlin rows (128 x 8 chunks = 1024 slots)
#pragma unroll
    for (int it = 0; it < 8; it++){
      const int slot = t + it * 128, row = slot >> 3, ch = slot & 7;
      st8bf(&wl[row * XS_STR + ch * 8], Wlin, fw, (size_t)row * I_ + kt + ch * 8);
    }
    __syncthreads();
#pragma unroll
    for (int ks = 0; ks < 2; ks++){
      const int k0 = ks * 32 + q * 8;
      const bf16x8 af = *reinterpret_cast<const bf16x8*>(&xs[(w * 16 + m16) * XS_STR + k0]);
#pragma unroll
      for (int nt = 0; nt < 8; nt++){
        const bf16x8 bfr = *reinterpret_cast<const bf16x8*>(&wl[(nt * 16 + m16) * XS_STR + k0]);
        acc[nt] = MFMA16(af, bfr, acc[nt]);
      }
    }
  }
#pragma unroll
  for (int nt = 0; nt < 8; nt++){
#pragma unroll
    for (int r = 0; r < 4; r++){
      const int n = n0 + w * 16 + q * 4 + r;
      const int col = nt * 16 + m16;
      const float v = (n == N_) ? ldv(prior, fpf, b * O_ + col) : acc[nt][r];
      hpb[((size_t)b * N1 + n) * O_ + col] = f2bf(v);
    }
  }
}

// ---- K2 (MFMA): hph = hp @ w_head[h]; tanh -> s_src/s_dst ----
// 64 rows x 128 cols per block; 256 thr (4 waves); full K=128 in LDS.
__global__ __launch_bounds__(256) void k2_heads(const u16* __restrict__ hpb,
                                                const u16* __restrict__ wT,
                                                const void* __restrict__ a_src,
                                                const void* __restrict__ a_dst,
                                                const int* __restrict__ flags,
                                                float* __restrict__ hph,
                                                float* __restrict__ s_src,
                                                float* __restrict__ s_dst){
  __shared__ __align__(16) u16 hsb[64 * HS_STR];    // 17.4 KB
  __shared__ __align__(16) u16 wtb[128 * HS_STR];   // 34.8 KB
  const int fas = flags[5], fad = flags[6];
  const int tile = blockIdx.x & 31;
  const int h    = (blockIdx.x >> 5) & 3;
  const int b    = blockIdx.x >> 7;
  const int bh   = b * H_ + h;
  const int n0   = tile * 64;
  const int t = threadIdx.x;
  const int w = t >> 6, lane = t & 63, m16 = lane & 15, q = lane >> 4;
  // stage hp rows (64 x 16 chunks = 1024 slots)
#pragma unroll
  for (int it = 0; it < 4; it++){
    const int slot = t + it * 256, row = slot >> 4, ch = slot & 15;
    *reinterpret_cast<uint4*>(&hsb[row * HS_STR + ch * 8]) =
      *reinterpret_cast<const uint4*>(&hpb[((size_t)b * N1 + n0 + row) * O_ + ch * 8]);
  }
  // stage wT rows (128 x 16 chunks = 2048 slots)
#pragma unroll
  for (int it = 0; it < 8; it++){
    const int slot = t + it * 256, row = slot >> 4, ch = slot & 15;
    *reinterpret_cast<uint4*>(&wtb[row * HS_STR + ch * 8]) =
      *reinterpret_cast<const uint4*>(&wT[((size_t)h * O_ + row) * O_ + ch * 8]);
  }
  __syncthreads();
  f32x4 acc[8];
#pragma unroll
  for (int nt = 0; nt < 8; nt++) acc[nt] = (f32x4){0.f, 0.f, 0.f, 0.f};
#pragma unroll
  for (int ks = 0; ks < 4; ks++){
    const int k0 = ks * 32 + q * 8;
    const bf16x8 af = *reinterpret_cast<const bf16x8*>(&hsb[(w * 16 + m16) * HS_STR + k0]);
#pragma unroll
    for (int nt = 0; nt < 8; nt++){
      const bf16x8 bfr = *reinterpret_cast<const bf16x8*>(&wtb[(nt * 16 + m16) * HS_STR + k0]);
      acc[nt] = MFMA16(af, bfr, acc[nt]);
    }
  }
  // epilogue: clamp, store hph fp32, tanh -> per-row score partials
  float ps[4] = {0.f, 0.f, 0.f, 0.f}, pd[4] = {0.f, 0.f, 0.f, 0.f};
#pragma unroll
  for (int nt = 0; nt < 8; nt++){
    const int col = nt * 16 + m16;
    const float asv = ldv(a_src, fas, h * O_ + col);
    const float adv = ldv(a_dst, fad, h * O_ + col);
#pragma unroll
    for (int r = 0; r < 4; r++){
      const float v = clH(acc[nt][r]);
      hph[((size_t)bh * N1 + n0 + w * 16 + q * 4 + r) * O_ + col] = v;
      const float tv = tanhf(v);
      ps[r] += tv * asv;
      pd[r] += tv * adv;
    }
  }
#pragma unroll
  for (int r = 0; r < 4; r++){
#pragma unroll
    for (int m = 8; m > 0; m >>= 1){
      ps[r] += __shfl_xor(ps[r], m);
      pd[r] += __shfl_xor(pd[r], m);
    }
    if (m16 == 0){
      const int n = n0 + w * 16 + q * 4 + r;
      s_src[(size_t)bh * N1 + n] = ps[r];
      s_dst[(size_t)bh * N1 + n] = pd[r];
    }
  }
}

// ---- K2b: min/max of s_dst over unmasked j ----
__global__ __launch_bounds__(256) void k2b_range(const float* __restrict__ s_dst,
                                                 const u8* __restrict__ mask,
                                                 const int* __restrict__ flags,
                                                 float* __restrict__ sdlo,
                                                 float* __restrict__ sdinv){
  __shared__ float smn[4], smx[4];
  const int bh = blockIdx.x, b = bh / H_, t = threadIdx.x;
  const int md = flags[0];
  float mn = 3e38f, mx = -3e38f;
  for (int j = t; j < N1; j += 256){
    if (!rdmask(mask, md, b * N1 + j)){
      float v = clS(s_dst[(size_t)bh * N1 + j]);
      mn = fminf(mn, v); mx = fmaxf(mx, v);
    }
  }
#pragma unroll
  for (int sft = 32; sft > 0; sft >>= 1){
    mn = fminf(mn, __shfl_down(mn, sft));
    mx = fmaxf(mx, __shfl_down(mx, sft));
  }
  if ((t & 63) == 0){ smn[t >> 6] = mn; smx[t >> 6] = mx; }
  __syncthreads();
  if (t == 0){
    mn = fminf(fminf(smn[0], smn[1]), fminf(smn[2], smn[3]));
    mx = fmaxf(fmaxf(smx[0], smx[1]), fmaxf(smx[2], smx[3]));
    float range = mx - mn;
    if (!(range > 1e-30f)) range = 1.f;
    sdlo[bh]  = mn;
    sdinv[bh] = (float)NBINS / range;
  }
}

// ---- K2c: colsum[bh][o] = sum_j hph[bh][j][o]  (grid 16 bh x 16 jchunks) ----
__global__ __launch_bounds__(256) void k2c_colsum(const float* __restrict__ hph,
                                                  float* __restrict__ colsum){
  const int bh = blockIdx.x >> 4, jc = blockIdx.x & 15;
  const int t = threadIdx.x, o = t & 127, half = t >> 7;
  const int j0 = jc * 128 + half * 64;
  float s = 0.f;
  for (int j = j0; j < j0 + 64; j++) s += hph[((size_t)bh * N1 + j) * O_ + o];
  atomicAdd(&colsum[bh * O_ + o], s);
}

// ---- K3a: counting sort of unmasked j by bin ----
__global__ __launch_bounds__(256) void k3a_bucket(const float* __restrict__ s_dst,
                                                  const u8* __restrict__ mask,
                                                  const int* __restrict__ flags,
                                                  const float* __restrict__ sdlo,
                                                  const float* __restrict__ sdinv,
                                                  int* __restrict__ binStart,
                                                  int* __restrict__ order){
  __shared__ int cnt[NBINS];
  __shared__ int part[256];
  __shared__ int offs[NBINS];
  const int bh = blockIdx.x, b = bh / H_, t = threadIdx.x;
  const int md = flags[0];
  const float lo = sdlo[bh], inv = sdinv[bh];
  cnt[t] = 0;
  __syncthreads();
  for (int j = t; j < N1; j += 256){
    if (!rdmask(mask, md, b * N1 + j))
      atomicAdd(&cnt[binOf(clS(s_dst[(size_t)bh * N1 + j]), lo, inv)], 1);
  }
  __syncthreads();
  const int mysum = cnt[t];
  part[t] = mysum;
  __syncthreads();
  for (int off = 1; off < 256; off <<= 1){
    int v = (t >= off) ? part[t - off] : 0;
    __syncthreads();
    part[t] += v;
    __syncthreads();
  }
  const int excl = part[t] - mysum;
  offs[t] = excl;
  binStart[bh * (NBINS + 1) + t] = excl;
  if (t == 255) binStart[bh * (NBINS + 1) + NBINS] = part[255];
  __syncthreads();
  for (int j = t; j < N1; j += 256){
    if (!rdmask(mask, md, b * N1 + j)){
      int bin = binOf(clS(s_dst[(size_t)bh * N1 + j]), lo, inv);
      int pos = atomicAdd(&offs[bin], 1);
      order[(size_t)bh * N1 + pos] = j;
    }
  }
}

// ---- K3b: per-bin sums (channel 128 = ones) ----
__global__ __launch_bounds__(192) void k3b_binsum(const float* __restrict__ hph,
                                                  const float* __restrict__ s_dst,
                                                  const int* __restrict__ binStart,
                                                  const int* __restrict__ order,
                                                  float* __restrict__ binPos,
                                                  float* __restrict__ binNeg){
  const int gb = blockIdx.x;
  const int bh = gb / NBINS, bin = gb % NBINS;
  const int t = threadIdx.x;
  const int s = binStart[bh * (NBINS + 1) + bin];
  const int e = binStart[bh * (NBINS + 1) + bin + 1];
  float ap = 0.f, an = 0.f;
  for (int m = s; m < e; m++){
    const int j = order[(size_t)bh * N1 + m];
    const float sdj = clS(s_dst[(size_t)bh * N1 + j]);
    const float fp = __expf(sdj), fn = __expf(SLOPEC * sdj);
    const float v = (t < O_) ? hph[((size_t)bh * N1 + j) * O_ + t] : 1.f;
    ap += fp * v; an += fn * v;
  }
  if (t <= O_){
    const size_t basei = ((size_t)bh * NBINS + bin) * STR;
    binPos[basei + t] = ap;
    binNeg[basei + t] = an;
  }
}

// ---- K3c: prefix/suffix over bins ----
__global__ __launch_bounds__(64) void k3c_prefix(const float* __restrict__ binPos,
                                                 const float* __restrict__ binNeg,
                                                 float* __restrict__ sufPos,
                                                 float* __restrict__ preNeg){
  const int idx = blockIdx.x * 64 + threadIdx.x;
  if (idx >= 2 * B_ * H_ * 129) return;
  const int ch  = idx % 129;
  const int g   = idx / 129;
  const int bh  = g % (B_ * H_);
  const int arr = g / (B_ * H_);
  if (arr == 0){
    float acc = 0.f;
    for (int r = 0; r < NBINS; r++){
      preNeg[((size_t)bh * (NBINS + 1) + r) * STR + ch] = acc;
      acc += binNeg[((size_t)bh * NBINS + r) * STR + ch];
    }
    preNeg[((size_t)bh * (NBINS + 1) + NBINS) * STR + ch] = acc;
  } else {
    float acc = 0.f;
    sufPos[((size_t)bh * (NBINS + 1) + NBINS) * STR + ch] = 0.f;
    for (int r = NBINS - 1; r >= 0; r--){
      acc += binPos[((size_t)bh * NBINS + r) * STR + ch];
      sufPos[((size_t)bh * (NBINS + 1) + r) * STR + ch] = acc;
    }
  }
}

// ---- K3d: output rows; heads parallel across 512-thr block ----
__global__ __launch_bounds__(512) void k3d_out(const float* __restrict__ hph,
                                               const float* __restrict__ s_src,
                                               const float* __restrict__ s_dst,
                                               const u8* __restrict__ mask,
                                               const int* __restrict__ flags,
                                               const float* __restrict__ sdlo,
                                               const float* __restrict__ sdinv,
                                               const int* __restrict__ binStart,
                                               const int* __restrict__ order,
                                               const float* __restrict__ sufPos,
                                               const float* __restrict__ preNeg,
                                               const float* __restrict__ colsum,
                                               const void* __restrict__ bias,
                                               void* __restrict__ outp){
  __shared__ float part[4][O_];
  const int blk = blockIdx.x;
  const int b = blk / N1, i = blk % N1;
  const int t = threadIdx.x;
  const int h = t >> 7, o = t & 127;
  const int md = flags[0], fo = flags[1];
  const bool mrow = rdmask(mask, md, b * N1 + i) != 0;
  const int bh = b * H_ + h;
  const int U = binStart[bh * (NBINS + 1) + NBINS];
  float contrib;
  if (mrow || U == 0){
    contrib = colsum[bh * O_ + o] * (1.f / N1);
  } else {
    const float si = clS(s_src[(size_t)bh * N1 + i]);
    const float tthr = -si;
    const int c = binOf(tthr, sdlo[bh], sdinv[bh]);
    const size_t rowp = ((size_t)bh * (NBINS + 1) + c + 1) * STR;
    const size_t rown = ((size_t)bh * (NBINS + 1) + c) * STR;
    float posV = sufPos[rowp + o], posS = sufPos[rowp + O_];
    float negV = preNeg[rown + o], negS = preNeg[rown + O_];
    const int s0 = binStart[bh * (NBINS + 1) + c];
    const int e0 = binStart[bh * (NBINS + 1) + c + 1];
    for (int m = s0; m < e0; m++){
      const int j = order[(size_t)bh * N1 + m];
      const float sdj = clS(s_dst[(size_t)bh * N1 + j]);
      const float hv = hph[((size_t)bh * N1 + j) * O_ + o];
      if (sdj >= tthr){ const float fp = __expf(sdj);          posV += fp * hv; posS += fp; }
      else            { const float fn = __expf(SLOPEC * sdj); negV += fn * hv; negS += fn; }
    }
    const float esi = __expf(si), esi2 = __expf(SLOPEC * si);
    const float den = fmaxf(esi * posS + esi2 * negS, 1e-35f);
    contrib = (esi * posV + esi2 * negV) / den;
  }
  part[h][o] = contrib;
  __syncthreads();
  if (t < O_){
    const float sum = part[0][t] + part[1][t] + part[2][t] + part[3][t];
    const float v = 0.25f * sum + ldv(bias, fo, t);
    const size_t oidx = ((size_t)b * N1 + i) * O_ + t;
    if (fo) ((u16*)outp)[oidx] = f2bf(v);
    else    ((float*)outp)[oidx] = v;
  }
}

extern "C" void kernel_launch(void* const* d_in, const int* in_sizes, int n_in,
                              void* d_out, int out_size, void* d_ws, size_t ws_size,
                              hipStream_t stream){
  const void* x      = d_in[0];
  const void* prior  = d_in[1];
  const u8*   mask   = (const u8*)d_in[2];
  const void* Wlin   = d_in[3];
  const void* w_head = d_in[4];
  const void* a_src  = d_in[5];
  const void* a_dst  = d_in[6];
  const void* bias   = d_in[7];

  char* basep = (char*)d_ws;
  size_t off = 0;
  auto alloc = [&](size_t bytes) -> void* {
    off = (off + 255) & ~(size_t)255;
    void* p = basep + off;
    off += bytes;
    return p;
  };
  int*   flags    = (int*)alloc(32);
  u16*   wT       = (u16*)alloc((size_t)H_ * O_ * O_ * 2);             // 128 KB
  u16*   hpb      = (u16*)alloc((size_t)B_ * N1 * O_ * 2);             // 2 MB
  float* hph      = (float*)alloc((size_t)B_ * H_ * N1 * O_ * 4);      // 16 MB
  float* s_src    = (float*)alloc((size_t)B_ * H_ * N1 * 4);
  float* s_dst    = (float*)alloc((size_t)B_ * H_ * N1 * 4);
  float* sdlo     = (float*)alloc(B_ * H_ * 4);
  float* sdinv    = (float*)alloc(B_ * H_ * 4);
  float* colsum   = (float*)alloc((size_t)B_ * H_ * O_ * 4);
  int*   binStart = (int*)alloc((size_t)B_ * H_ * (NBINS + 1) * 4);
  int*   order    = (int*)alloc((size_t)B_ * H_ * N1 * 4);
  float* binPos   = (float*)alloc((size_t)B_ * H_ * NBINS * STR * 4);
  float* binNeg   = (float*)alloc((size_t)B_ * H_ * NBINS * STR * 4);
  float* sufPos   = (float*)alloc((size_t)B_ * H_ * (NBINS + 1) * STR * 4);
  float* preNeg   = (float*)alloc((size_t)B_ * H_ * (NBINS + 1) * STR * 4);
  (void)in_sizes; (void)n_in; (void)out_size; (void)ws_size;   // ~25 MB used

  hipLaunchKernelGGL(k0_detect,  dim3(1),               dim3(256), 0, stream, mask, x, prior, Wlin, w_head, a_src, a_dst, flags, colsum);
  hipLaunchKernelGGL(ktr,        dim3(256),             dim3(256), 0, stream, w_head, flags, wT);
  hipLaunchKernelGGL(k1_hp,      dim3(B_ * 64),         dim3(128), 0, stream, x, prior, Wlin, flags, hpb);
  hipLaunchKernelGGL(k2_heads,   dim3(B_ * H_ * 32),    dim3(256), 0, stream, hpb, wT, a_src, a_dst, flags, hph, s_src, s_dst);
  hipLaunchKernelGGL(k2b_range,  dim3(B_ * H_),         dim3(256), 0, stream, s_dst, mask, flags, sdlo, sdinv);
  hipLaunchKernelGGL(k2c_colsum, dim3(B_ * H_ * 16),    dim3(256), 0, stream, hph, colsum);
  hipLaunchKernelGGL(k3a_bucket, dim3(B_ * H_),         dim3(256), 0, stream, s_dst, mask, flags, sdlo, sdinv, binStart, order);
  hipLaunchKernelGGL(k3b_binsum, dim3(B_ * H_ * NBINS), dim3(192), 0, stream, hph, s_dst, binStart, order, binPos, binNeg);
  hipLaunchKernelGGL(k3c_prefix, dim3((2 * B_ * H_ * 129 + 63) / 64), dim3(64), 0, stream, binPos, binNeg, sufPos, preNeg);
  hipLaunchKernelGGL(k3d_out,    dim3(B_ * N1),         dim3(512), 0, stream, hph, s_src, s_dst, mask, flags, sdlo, sdinv, binStart, order, sufPos, preNeg, colsum, bias, d_out);
}

// Round 9
// 226.519 us; speedup vs baseline: 1.8129x; 1.1126x over previous
//
#include <hip/hip_runtime.h>
#include <hip/hip_bf16.h>
#include <cmath>

// GAT layer.  B=4, N=2047 (+1 prior), I=256, O=128, H=4.  bf16 in/out.
// exp(leakyrelu(si+sj)) factorizes per branch; bucket j by s_dst (256 bins),
// per-bin channel sums, prefix/suffix over bins, boundary bin element-wise.
// R9: latency-chain fixes — k3d batched boundary loads (4 rows/block),
// k3b LDS member staging, k3c hierarchical scan, k0 1024 thr, k1 4 waves,
// colsum fused into k2 epilogue (k2c removed).

#define B_ 4
#define N_ 2047
#define N1 2048
#define I_ 256
#define O_ 128
#define H_ 4
#define NBINS 256
#define STR 132
#define SLOPEC 0.2f
#define HS_STR 136
#define XS_STR 72
#define CAP 8

typedef unsigned short u16;
typedef unsigned char u8;
typedef short bf16x8 __attribute__((ext_vector_type(8)));
typedef float f32x4 __attribute__((ext_vector_type(4)));
#define MFMA16(a,b,c) __builtin_amdgcn_mfma_f32_16x16x32_bf16(a,b,c,0,0,0)

__device__ __forceinline__ float bf2f(u16 v){
  union { unsigned u; float f; } x; x.u = ((unsigned)v) << 16; return x.f;
}
__device__ __forceinline__ u16 f2bf(float f){
  union { float f; unsigned u; } x; x.f = f;
  unsigned u = x.u;
  return (u16)((u + 0x7FFFu + ((u >> 16) & 1u)) >> 16);
}
__device__ __forceinline__ float ldv(const void* p, int bf, size_t i){
  if (bf) return bf2f(reinterpret_cast<const u16*>(p)[i]);
  return reinterpret_cast<const float*>(p)[i];
}
__device__ __forceinline__ void ld8(const void* p, int bf, size_t i, float* o){
  if (bf){
    uint4 v = *reinterpret_cast<const uint4*>(reinterpret_cast<const u16*>(p) + i);
    o[0]=bf2f((u16)(v.x&0xFFFF)); o[1]=bf2f((u16)(v.x>>16));
    o[2]=bf2f((u16)(v.y&0xFFFF)); o[3]=bf2f((u16)(v.y>>16));
    o[4]=bf2f((u16)(v.z&0xFFFF)); o[5]=bf2f((u16)(v.z>>16));
    o[6]=bf2f((u16)(v.w&0xFFFF)); o[7]=bf2f((u16)(v.w>>16));
  } else {
    const float4* q = reinterpret_cast<const float4*>(reinterpret_cast<const float*>(p) + i);
    float4 a = q[0], b = q[1];
    o[0]=a.x; o[1]=a.y; o[2]=a.z; o[3]=a.w;
    o[4]=b.x; o[5]=b.y; o[6]=b.z; o[7]=b.w;
  }
}
__device__ __forceinline__ void st8bf(u16* dst, const void* src, int bf, size_t i){
  if (bf){
    *reinterpret_cast<uint4*>(dst) =
      *reinterpret_cast<const uint4*>(reinterpret_cast<const u16*>(src) + i);
  } else {
    float v[8]; ld8(src, 0, i, v);
    u16 tmp[8];
#pragma unroll
    for (int m = 0; m < 8; m++) tmp[m] = f2bf(v[m]);
    *reinterpret_cast<uint4*>(dst) = *reinterpret_cast<uint4*>(tmp);
  }
}
__device__ __forceinline__ float clS(float v){ return fminf(30.f, fmaxf(-30.f, v)); }
__device__ __forceinline__ float clH(float v){ return fminf(1e4f, fmaxf(-1e4f, v)); }
__device__ __forceinline__ int binOf(float v, float lo, float inv){
  int c = (int)((v - lo) * inv);
  c = c < 0 ? 0 : c;
  c = c > NBINS - 1 ? NBINS - 1 : c;
  return c;
}
__device__ __forceinline__ int rdmask(const u8* m, int mode, int idx){
  return mode ? (m[idx] != 0) : (((const int*)m)[idx] != 0);
}

__global__ __launch_bounds__(1024) void k0_detect(const u8* __restrict__ mask,
                                                  const void* x, const void* prior,
                                                  const void* Wlin, const void* wh,
                                                  const void* asr, const void* ads,
                                                  int* __restrict__ flags,
                                                  float* __restrict__ colsum){
  __shared__ int c[8];
  const int t = threadIdx.x;
  for (int i = t; i < B_ * H_ * O_; i += 1024) colsum[i] = 0.f;
  if (t < 8) c[t] = 0;
  __syncthreads();
  int local = 0;
  for (int i = t; i < B_ * N1; i += 1024)
    if ((i & 3) && mask[i]) local = 1;
  if (local) atomicOr(&c[0], 1);
  const void* ptrs[6] = {x, prior, Wlin, wh, asr, ads};
  const int   lens[6] = {4096, 512, 4096, 4096, 512, 512};
  for (int k = 0; k < 6; k++){
    const u16* p = (const u16*)ptrs[k];
    int g = 0;
    for (int i = t; i < lens[k]; i += 1024){
      int e = (p[i] >> 7) & 0xFF;
      if (e >= 0xC0) g++;
    }
    if (g) atomicAdd(&c[k + 1], g);
  }
  __syncthreads();
  if (t == 0) flags[0] = c[0];
  else if (t <= 6) flags[t] = (c[t] < 4) ? 1 : 0;
}

__global__ __launch_bounds__(256) void ktr(const void* __restrict__ w_head,
                                           const int* __restrict__ flags,
                                           u16* __restrict__ wT){
  const int fw = flags[4];
  const int idx = blockIdx.x * 256 + threadIdx.x;
  const int h = idx >> 14, rem = idx & 16383, p = rem >> 7, o = rem & 127;
  wT[idx] = f2bf(ldv(w_head, fw, ((size_t)h * O_ + o) * O_ + p));
}

__global__ __launch_bounds__(256) void k1_hp(const void* __restrict__ x,
                                             const void* __restrict__ prior,
                                             const void* __restrict__ Wlin,
                                             const int* __restrict__ flags,
                                             u16* __restrict__ hpb){
  __shared__ __align__(16) u16 xs[32 * XS_STR];
  __shared__ __align__(16) u16 wl[128 * XS_STR];
  const int fx = flags[1], fpf = flags[2], fw = flags[3];
  const int tile = blockIdx.x & 63;
  const int b    = blockIdx.x >> 6;
  const int n0   = tile * 32;
  const int t = threadIdx.x;
  const int w = t >> 6, lane = t & 63, m16 = lane & 15, q = lane >> 4;
  const int rbase = (w & 1) * 16;
  const int cbase = (w >> 1) * 64;
  f32x4 acc[4];
#pragma unroll
  for (int nt = 0; nt < 4; nt++) acc[nt] = (f32x4){0.f, 0.f, 0.f, 0.f};
  for (int kt = 0; kt < I_; kt += 64){
    if (kt) __syncthreads();
    {
      const int row = t >> 3, ch = t & 7;
      const int n = n0 + row;
      if (n < N_) st8bf(&xs[row * XS_STR + ch * 8], x, fx, ((size_t)b * N_ + n) * I_ + kt + ch * 8);
      else { uint4 z = make_uint4(0,0,0,0); *reinterpret_cast<uint4*>(&xs[row * XS_STR + ch * 8]) = z; }
    }
#pragma unroll
    for (int it = 0; it < 4; it++){
      const int slot = t + it * 256, row = slot >> 3, ch = slot & 7;
      st8bf(&wl[row * XS_STR + ch * 8], Wlin, fw, (size_t)row * I_ + kt + ch * 8);
    }
    __syncthreads();
#pragma unroll
    for (int ks = 0; ks < 2; ks++){
      const int k0 = ks * 32 + q * 8;
      const bf16x8 af = *reinterpret_cast<const bf16x8*>(&xs[(rbase + m16) * XS_STR + k0]);
#pragma unroll
      for (int nt = 0; nt < 4; nt++){
        const bf16x8 bfr = *reinterpret_cast<const bf16x8*>(&wl[(cbase + nt * 16 + m16) * XS_STR + k0]);
        acc[nt] = MFMA16(af, bfr, acc[nt]);
      }
    }
  }
#pragma unroll
  for (int nt = 0; nt < 4; nt++){
#pragma unroll
    for (int r = 0; r < 4; r++){
      const int n = n0 + rbase + q * 4 + r;
      const int col = cbase + nt * 16 + m16;
      const float v = (n == N_) ? ldv(prior, fpf, b * O_ + col) : acc[nt][r];
      hpb[((size_t)b * N1 + n) * O_ + col] = f2bf(v);
    }
  }
}

__global__ __launch_bounds__(256) void k2_heads(const u16* __restrict__ hpb,
                                                const u16* __restrict__ wT,
                                                const void* __restrict__ a_src,
                                                const void* __restrict__ a_dst,
                                                const int* __restrict__ flags,
                                                float* __restrict__ hph,
                                                float* __restrict__ s_src,
                                                float* __restrict__ s_dst,
                                                float* __restrict__ colsum){
  __shared__ __align__(16) u16 hsb[64 * HS_STR];
  __shared__ __align__(16) u16 wtb[128 * HS_STR];
  __shared__ float colacc[O_];
  const int fas = flags[5], fad = flags[6];
  const int tile = blockIdx.x & 31;
  const int h    = (blockIdx.x >> 5) & 3;
  const int b    = blockIdx.x >> 7;
  const int bh   = b * H_ + h;
  const int n0   = tile * 64;
  const int t = threadIdx.x;
  const int w = t >> 6, lane = t & 63, m16 = lane & 15, q = lane >> 4;
  if (t < O_) colacc[t] = 0.f;
#pragma unroll
  for (int it = 0; it < 4; it++){
    const int slot = t + it * 256, row = slot >> 4, ch = slot & 15;
    *reinterpret_cast<uint4*>(&hsb[row * HS_STR + ch * 8]) =
      *reinterpret_cast<const uint4*>(&hpb[((size_t)b * N1 + n0 + row) * O_ + ch * 8]);
  }
#pragma unroll
  for (int it = 0; it < 8; it++){
    const int slot = t + it * 256, row = slot >> 4, ch = slot & 15;
    *reinterpret_cast<uint4*>(&wtb[row * HS_STR + ch * 8]) =
      *reinterpret_cast<const uint4*>(&wT[((size_t)h * O_ + row) * O_ + ch * 8]);
  }
  __syncthreads();
  f32x4 acc[8];
#pragma unroll
  for (int nt = 0; nt < 8; nt++) acc[nt] = (f32x4){0.f, 0.f, 0.f, 0.f};
#pragma unroll
  for (int ks = 0; ks < 4; ks++){
    const int k0 = ks * 32 + q * 8;
    const bf16x8 af = *reinterpret_cast<const bf16x8*>(&hsb[(w * 16 + m16) * HS_STR + k0]);
#pragma unroll
    for (int nt = 0; nt < 8; nt++){
      const bf16x8 bfr = *reinterpret_cast<const bf16x8*>(&wtb[(nt * 16 + m16) * HS_STR + k0]);
      acc[nt] = MFMA16(af, bfr, acc[nt]);
    }
  }
  float ps[4] = {0.f, 0.f, 0.f, 0.f}, pd[4] = {0.f, 0.f, 0.f, 0.f};
#pragma unroll
  for (int nt = 0; nt < 8; nt++){
    const int col = nt * 16 + m16;
    const float asv = ldv(a_src, fas, h * O_ + col);
    const float adv = ldv(a_dst, fad, h * O_ + col);
    float colpart = 0.f;
#pragma unroll
    for (int r = 0; r < 4; r++){
      const float v = clH(acc[nt][r]);
      hph[((size_t)bh * N1 + n0 + w * 16 + q * 4 + r) * O_ + col] = v;
      colpart += v;
      const float tv = tanhf(v);
      ps[r] += tv * asv;
      pd[r] += tv * adv;
    }
    atomicAdd(&colacc[col], colpart);
  }
#pragma unroll
  for (int r = 0; r < 4; r++){
#pragma unroll
    for (int m = 8; m > 0; m >>= 1){
      ps[r] += __shfl_xor(ps[r], m);
      pd[r] += __shfl_xor(pd[r], m);
    }
    if (m16 == 0){
      const int n = n0 + w * 16 + q * 4 + r;
      s_src[(size_t)bh * N1 + n] = ps[r];
      s_dst[(size_t)bh * N1 + n] = pd[r];
    }
  }
  __syncthreads();
  if (t < O_) atomicAdd(&colsum[bh * O_ + t], colacc[t]);
}

__global__ __launch_bounds__(256) void k2b_range(const float* __restrict__ s_dst,
                                                 const u8* __restrict__ mask,
                                                 const int* __restrict__ flags,
                                                 float* __restrict__ sdlo,
                                                 float* __restrict__ sdinv){
  __shared__ float smn[4], smx[4];
  const int bh = blockIdx.x, b = bh / H_, t = threadIdx.x;
  const int md = flags[0];
  float mn = 3e38f, mx = -3e38f;
  for (int j = t; j < N1; j += 256){
    if (!rdmask(mask, md, b * N1 + j)){
      float v = clS(s_dst[(size_t)bh * N1 + j]);
      mn = fminf(mn, v); mx = fmaxf(mx, v);
    }
  }
#pragma unroll
  for (int sft = 32; sft > 0; sft >>= 1){
    mn = fminf(mn, __shfl_down(mn, sft));
    mx = fmaxf(mx, __shfl_down(mx, sft));
  }
  if ((t & 63) == 0){ smn[t >> 6] = mn; smx[t >> 6] = mx; }
  __syncthreads();
  if (t == 0){
    mn = fminf(fminf(smn[0], smn[1]), fminf(smn[2], smn[3]));
    mx = fmaxf(fmaxf(smx[0], smx[1]), fmaxf(smx[2], smx[3]));
    float range = mx - mn;
    if (!(range > 1e-30f)) range = 1.f;
    sdlo[bh]  = mn;
    sdinv[bh] = (float)NBINS / range;
  }
}

__global__ __launch_bounds__(256) void k3a_bucket(const float* __restrict__ s_dst,
                                                  const u8* __restrict__ mask,
                                                  const int* __restrict__ flags,
                                                  const float* __restrict__ sdlo,
                                                  const float* __restrict__ sdinv,
                                                  int* __restrict__ binStart,
                                                  int* __restrict__ order){
  __shared__ int cnt[NBINS];
  __shared__ int part[256];
  __shared__ int offs[NBINS];
  const int bh = blockIdx.x, b = bh / H_, t = threadIdx.x;
  const int md = flags[0];
  const float lo = sdlo[bh], inv = sdinv[bh];
  cnt[t] = 0;
  __syncthreads();
  for (int j = t; j < N1; j += 256){
    if (!rdmask(mask, md, b * N1 + j))
      atomicAdd(&cnt[binOf(clS(s_dst[(size_t)bh * N1 + j]), lo, inv)], 1);
  }
  __syncthreads();
  const int mysum = cnt[t];
  part[t] = mysum;
  __syncthreads();
  for (int off = 1; off < 256; off <<= 1){
    int v = (t >= off) ? part[t - off] : 0;
    __syncthreads();
    part[t] += v;
    __syncthreads();
  }
  const int excl = part[t] - mysum;
  offs[t] = excl;
  binStart[bh * (NBINS + 1) + t] = excl;
  if (t == 255) binStart[bh * (NBINS + 1) + NBINS] = part[255];
  __syncthreads();
  for (int j = t; j < N1; j += 256){
    if (!rdmask(mask, md, b * N1 + j)){
      int bin = binOf(clS(s_dst[(size_t)bh * N1 + j]), lo, inv);
      int pos = atomicAdd(&offs[bin], 1);
      order[(size_t)bh * N1 + pos] = j;
    }
  }
}

__global__ __launch_bounds__(192) void k3b_binsum(const float* __restrict__ hph,
                                                  const float* __restrict__ s_dst,
                                                  const int* __restrict__ binStart,
                                                  const int* __restrict__ order,
                                                  float* __restrict__ binPos,
                                                  float* __restrict__ binNeg){
  __shared__ int jls[64];
  __shared__ float fpl[64], fnl[64];
  const int gb = blockIdx.x;
  const int bh = gb / NBINS, bin = gb % NBINS;
  const int t = threadIdx.x;
  const int s = binStart[bh * (NBINS + 1) + bin];
  const int e = binStart[bh * (NBINS + 1) + bin + 1];
  float ap = 0.f, an = 0.f;
  for (int mb = s; mb < e; mb += 64){
    const int cn = min(64, e - mb);
    if (t < cn){
      const int j = order[(size_t)bh * N1 + mb + t];
      const float sdj = clS(s_dst[(size_t)bh * N1 + j]);
      jls[t] = j;
      fpl[t] = __expf(sdj);
      fnl[t] = __expf(SLOPEC * sdj);
    }
    __syncthreads();
    for (int m = 0; m < cn; m++){
      const float v = (t < O_) ? hph[((size_t)bh * N1 + jls[m]) * O_ + t] : 1.f;
      ap += fpl[m] * v;
      an += fnl[m] * v;
    }
    __syncthreads();
  }
  if (t <= O_){
    const size_t basei = ((size_t)bh * NBINS + bin) * STR;
    binPos[basei + t] = ap;
    binNeg[basei + t] = an;
  }
}

__global__ __launch_bounds__(256) void k3c1(const float* __restrict__ binPos,
                                            const float* __restrict__ binNeg,
                                            float* __restrict__ chunkSum){
  const int idx = blockIdx.x * 256 + threadIdx.x;
  if (idx >= 2 * 16 * 4 * 129) return;
  const int ch = idx % 129;
  int rest = idx / 129;
  const int chunk = rest & 3;
  rest >>= 2;
  const int bh = rest & 15;
  const int arr = rest >> 4;
  const float* src = arr ? binPos : binNeg;
  float s = 0.f;
  const size_t base = ((size_t)bh * NBINS + chunk * 64) * STR + ch;
  for (int r = 0; r < 64; r++) s += src[base + (size_t)r * STR];
  chunkSum[(((size_t)arr * 16 + bh) * 4 + chunk) * STR + ch] = s;
}

__global__ __launch_bounds__(256) void k3c2(const float* __restrict__ binPos,
                                            const float* __restrict__ binNeg,
                                            const float* __restrict__ chunkSum,
                                            float* __restrict__ sufPos,
                                            float* __restrict__ preNeg){
  const int idx = blockIdx.x * 256 + threadIdx.x;
  if (idx >= 2 * 16 * 4 * 129) return;
  const int ch = idx % 129;
  int rest = idx / 129;
  const int chunk = rest & 3;
  rest >>= 2;
  const int bh = rest & 15;
  const int arr = rest >> 4;
  if (arr == 0){
    float acc = 0.f;
    for (int cc = 0; cc < chunk; cc++)
      acc += chunkSum[(((size_t)bh) * 4 + cc) * STR + ch];
    for (int rr = 0; rr < 64; rr++){
      const int r = chunk * 64 + rr;
      preNeg[((size_t)bh * (NBINS + 1) + r) * STR + ch] = acc;
      acc += binNeg[((size_t)bh * NBINS + r) * STR + ch];
    }
    if (chunk == 3) preNeg[((size_t)bh * (NBINS + 1) + NBINS) * STR + ch] = acc;
  } else {
    float acc = 0.f;
    for (int cc = chunk + 1; cc < 4; cc++)
      acc += chunkSum[(((size_t)16 + bh) * 4 + cc) * STR + ch];
    for (int rr = 63; rr >= 0; rr--){
      const int r = chunk * 64 + rr;
      acc += binPos[((size_t)bh * NBINS + r) * STR + ch];
      sufPos[((size_t)bh * (NBINS + 1) + r) * STR + ch] = acc;
    }
    if (chunk == 3) sufPos[((size_t)bh * (NBINS + 1) + NBINS) * STR + ch] = 0.f;
  }
}

#define K3D_ROWS 4
__global__ __launch_bounds__(512) void k3d_out(const float* __restrict__ hph,
                                               const float* __restrict__ s_src,
                                               const float* __restrict__ s_dst,
                                               const u8* __restrict__ mask,
                                               const int* __restrict__ flags,
                                               const float* __restrict__ sdlo,
                                               const float* __restrict__ sdinv,
                                               const int* __restrict__ binStart,
                                               const int* __restrict__ order,
                                               const float* __restrict__ sufPos,
                                               const float* __restrict__ preNeg,
                                               const float* __restrict__ colsum,
                                               const void* __restrict__ bias,
                                               void* __restrict__ outp){
  __shared__ float part[4 * K3D_ROWS * STR];
  const int blk = blockIdx.x;
  const int b  = blk / (N1 / K3D_ROWS);
  const int i0 = (blk % (N1 / K3D_ROWS)) * K3D_ROWS;
  const int t = threadIdx.x;
  const int h = t >> 7, o = t & 127;
  const int md = flags[0], fo = flags[1];
  const int bh = b * H_ + h;
  const int U = binStart[bh * (NBINS + 1) + NBINS];
  const float lo = sdlo[bh], inv = sdinv[bh];
  const float cv = colsum[bh * O_ + o];

  int mrow[K3D_ROWS], s0[K3D_ROWS], nm[K3D_ROWS], nb[K3D_ROWS];
  float si[K3D_ROWS];
  float posV[K3D_ROWS], posS[K3D_ROWS], negV[K3D_ROWS], negS[K3D_ROWS];
#pragma unroll
  for (int r = 0; r < K3D_ROWS; r++){
    const int i = i0 + r;
    mrow[r] = rdmask(mask, md, b * N1 + i);
    si[r] = clS(s_src[(size_t)bh * N1 + i]);
  }
#pragma unroll
  for (int r = 0; r < K3D_ROWS; r++){
    const int c = binOf(-si[r], lo, inv);
    const size_t rowp = ((size_t)bh * (NBINS + 1) + c + 1) * STR;
    const size_t rown = ((size_t)bh * (NBINS + 1) + c) * STR;
    posV[r] = sufPos[rowp + o]; posS[r] = sufPos[rowp + O_];
    negV[r] = preNeg[rown + o]; negS[r] = preNeg[rown + O_];
    const int e0 = binStart[bh * (NBINS + 1) + c + 1];
    s0[r] = binStart[bh * (NBINS + 1) + c];
    nm[r] = (mrow[r] || U == 0) ? 0 : (e0 - s0[r]);
    nb[r] = nm[r] < CAP ? nm[r] : CAP;
  }
  int jj[K3D_ROWS][CAP];
#pragma unroll
  for (int r = 0; r < K3D_ROWS; r++){
    if (nm[r] > 0){
#pragma unroll
      for (int s = 0; s < CAP; s++){
        const int m = s0[r] + (s < nb[r] ? s : 0);
        jj[r][s] = order[(size_t)bh * N1 + m];
      }
    } else {
#pragma unroll
      for (int s = 0; s < CAP; s++) jj[r][s] = 0;
    }
  }
  float sd[K3D_ROWS][CAP];
#pragma unroll
  for (int r = 0; r < K3D_ROWS; r++){
    if (nm[r] > 0){
#pragma unroll
      for (int s = 0; s < CAP; s++)
        sd[r][s] = s_dst[(size_t)bh * N1 + jj[r][s]];
    }
  }
#pragma unroll
  for (int r = 0; r < K3D_ROWS; r++){
    if (nm[r] > 0){
      const float tthr = -si[r];
#pragma unroll
      for (int s = 0; s < CAP; s++){
        if (s < nb[r]){
          const float sdj = clS(sd[r][s]);
          const float hv = hph[((size_t)bh * N1 + jj[r][s]) * O_ + o];
          if (sdj >= tthr){ const float fp = __expf(sdj);          posV[r] += fp * hv; posS[r] += fp; }
          else            { const float fn = __expf(SLOPEC * sdj); negV[r] += fn * hv; negS[r] += fn; }
        }
      }
      for (int m = s0[r] + nb[r]; m < s0[r] + nm[r]; m++){
        const int j = order[(size_t)bh * N1 + m];
        const float sdj = clS(s_dst[(size_t)bh * N1 + j]);
        const float hv = hph[((size_t)bh * N1 + j) * O_ + o];
        if (sdj >= tthr){ const float fp = __expf(sdj);          posV[r] += fp * hv; posS[r] += fp; }
        else            { const float fn = __expf(SLOPEC * sdj); negV[r] += fn * hv; negS[r] += fn; }
      }
    }
  }
#pragma unroll
  for (int r = 0; r < K3D_ROWS; r++){
    float contrib;
    if (mrow[r] || U == 0){
      contrib = cv * (1.f / N1);
    } else {
      const float esi = __expf(si[r]), esi2 = __expf(SLOPEC * si[r]);
      const float den = fmaxf(esi * posS[r] + esi2 * negS[r], 1e-35f);
      contrib = (esi * posV[r] + esi2 * negV[r]) / den;
    }
    part[(h * K3D_ROWS + r) * STR + o] = contrib;
  }
  __syncthreads();
  {
    const int r = t >> 7, oc = t & 127;
    const float sum = part[(0 * K3D_ROWS + r) * STR + oc] + part[(1 * K3D_ROWS + r) * STR + oc]
                    + part[(2 * K3D_ROWS + r) * STR + oc] + part[(3 * K3D_ROWS + r) * STR + oc];
    const float v = 0.25f * sum + ldv(bias, fo, oc);
    const size_t oidx = ((size_t)b * N1 + i0 + r) * O_ + oc;
    if (fo) ((u16*)outp)[oidx] = f2bf(v);
    else    ((float*)outp)[oidx] = v;
  }
}

extern "C" void kernel_launch(void* const* d_in, const int* in_sizes, int n_in,
                              void* d_out, int out_size, void* d_ws, size_t ws_size,
                              hipStream_t stream){
  const void* x      = d_in[0];
  const void* prior  = d_in[1];
  const u8*   mask   = (const u8*)d_in[2];
  const void* Wlin   = d_in[3];
  const void* w_head = d_in[4];
  const void* a_src  = d_in[5];
  const void* a_dst  = d_in[6];
  const void* bias   = d_in[7];

  char* basep = (char*)d_ws;
  size_t off = 0;
  auto alloc = [&](size_t bytes) -> void* {
    off = (off + 255) & ~(size_t)255;
    void* p = basep + off;
    off += bytes;
    return p;
  };
  int*   flags    = (int*)alloc(32);
  u16*   wT       = (u16*)alloc((size_t)H_ * O_ * O_ * 2);
  u16*   hpb      = (u16*)alloc((size_t)B_ * N1 * O_ * 2);
  float* hph      = (float*)alloc((size_t)B_ * H_ * N1 * O_ * 4);
  float* s_src    = (float*)alloc((size_t)B_ * H_ * N1 * 4);
  float* s_dst    = (float*)alloc((size_t)B_ * H_ * N1 * 4);
  float* sdlo     = (float*)alloc(B_ * H_ * 4);
  float* sdinv    = (float*)alloc(B_ * H_ * 4);
  float* colsum   = (float*)alloc((size_t)B_ * H_ * O_ * 4);
  int*   binStart = (int*)alloc((size_t)B_ * H_ * (NBINS + 1) * 4);
  int*   order    = (int*)alloc((size_t)B_ * H_ * N1 * 4);
  float* binPos   = (float*)alloc((size_t)B_ * H_ * NBINS * STR * 4);
  float* binNeg   = (float*)alloc((size_t)B_ * H_ * NBINS * STR * 4);
  float* sufPos   = (float*)alloc((size_t)B_ * H_ * (NBINS + 1) * STR * 4);
  float* preNeg   = (float*)alloc((size_t)B_ * H_ * (NBINS + 1) * STR * 4);
  float* chunkSum = (float*)alloc((size_t)2 * 16 * 4 * STR * 4);
  (void)in_sizes; (void)n_in; (void)out_size; (void)ws_size;

  const int scanN = 2 * 16 * 4 * 129;
  hipLaunchKernelGGL(k0_detect,  dim3(1),                   dim3(1024), 0, stream, mask, x, prior, Wlin, w_head, a_src, a_dst, flags, colsum);
  hipLaunchKernelGGL(ktr,        dim3(256),                 dim3(256), 0, stream, w_head, flags, wT);
  hipLaunchKernelGGL(k1_hp,      dim3(B_ * 64),             dim3(256), 0, stream, x, prior, Wlin, flags, hpb);
  hipLaunchKernelGGL(k2_heads,   dim3(B_ * H_ * 32),        dim3(256), 0, stream, hpb, wT, a_src, a_dst, flags, hph, s_src, s_dst, colsum);
  hipLaunchKernelGGL(k2b_range,  dim3(B_ * H_),             dim3(256), 0, stream, s_dst, mask, flags, sdlo, sdinv);
  hipLaunchKernelGGL(k3a_bucket, dim3(B_ * H_),             dim3(256), 0, stream, s_dst, mask, flags, sdlo, sdinv, binStart, order);
  hipLaunchKernelGGL(k3b_binsum, dim3(B_ * H_ * NBINS),     dim3(192), 0, stream, hph, s_dst, binStart, order, binPos, binNeg);
  hipLaunchKernelGGL(k3c1,       dim3((scanN + 255) / 256), dim3(256), 0, stream, binPos, binNeg, chunkSum);
  hipLaunchKernelGGL(k3c2,       dim3((scanN + 255) / 256), dim3(256), 0, stream, binPos, binNeg, chunkSum, sufPos, preNeg);
  hipLaunchKernelGGL(k3d_out,    dim3(B_ * N1 / K3D_ROWS),  dim3(512), 0, stream, hph, s_src, s_dst, mask, flags, sdlo, sdinv, binStart, order, sufPos, preNeg, colsum, bias, d_out);
}

// Round 11
// 161.162 us; speedup vs baseline: 2.5481x; 1.4055x over previous
//
#include <hip/hip_runtime.h>
#include <hip/hip_bf16.h>
#include <cmath>

// GAT layer.  B=4, N=2047 (+1 prior), I=256, O=128, H=4.  bf16 in/out.
// exp(leakyrelu(si+sj)) factorizes per branch; bucket j by s_dst (256 bins),
// per-bin channel sums, prefix/suffix over bins, boundary bin element-wise.
// R10 (resubmit; R10 bench was an infra failure): k3d reverted to 1-row/block
// high-occupancy form (R9's register batching dropped occupancy 56->17% and
// regressed 52->93us); member chain replaced by wave-shuffle broadcast +
// 4-unrolled independent hph gathers.  k2b merged into k3a.

#define B_ 4
#define N_ 2047
#define N1 2048
#define I_ 256
#define O_ 128
#define H_ 4
#define NBINS 256
#define STR 132
#define SLOPEC 0.2f
#define HS_STR 136
#define XS_STR 72

typedef unsigned short u16;
typedef unsigned char u8;
typedef short bf16x8 __attribute__((ext_vector_type(8)));
typedef float f32x4 __attribute__((ext_vector_type(4)));
#define MFMA16(a,b,c) __builtin_amdgcn_mfma_f32_16x16x32_bf16(a,b,c,0,0,0)

__device__ __forceinline__ float bf2f(u16 v){
  union { unsigned u; float f; } x; x.u = ((unsigned)v) << 16; return x.f;
}
__device__ __forceinline__ u16 f2bf(float f){
  union { float f; unsigned u; } x; x.f = f;
  unsigned u = x.u;
  return (u16)((u + 0x7FFFu + ((u >> 16) & 1u)) >> 16);
}
__device__ __forceinline__ float ldv(const void* p, int bf, size_t i){
  if (bf) return bf2f(reinterpret_cast<const u16*>(p)[i]);
  return reinterpret_cast<const float*>(p)[i];
}
__device__ __forceinline__ void ld8(const void* p, int bf, size_t i, float* o){
  if (bf){
    uint4 v = *reinterpret_cast<const uint4*>(reinterpret_cast<const u16*>(p) + i);
    o[0]=bf2f((u16)(v.x&0xFFFF)); o[1]=bf2f((u16)(v.x>>16));
    o[2]=bf2f((u16)(v.y&0xFFFF)); o[3]=bf2f((u16)(v.y>>16));
    o[4]=bf2f((u16)(v.z&0xFFFF)); o[5]=bf2f((u16)(v.z>>16));
    o[6]=bf2f((u16)(v.w&0xFFFF)); o[7]=bf2f((u16)(v.w>>16));
  } else {
    const float4* q = reinterpret_cast<const float4*>(reinterpret_cast<const float*>(p) + i);
    float4 a = q[0], b = q[1];
    o[0]=a.x; o[1]=a.y; o[2]=a.z; o[3]=a.w;
    o[4]=b.x; o[5]=b.y; o[6]=b.z; o[7]=b.w;
  }
}
__device__ __forceinline__ void st8bf(u16* dst, const void* src, int bf, size_t i){
  if (bf){
    *reinterpret_cast<uint4*>(dst) =
      *reinterpret_cast<const uint4*>(reinterpret_cast<const u16*>(src) + i);
  } else {
    float v[8]; ld8(src, 0, i, v);
    u16 tmp[8];
#pragma unroll
    for (int m = 0; m < 8; m++) tmp[m] = f2bf(v[m]);
    *reinterpret_cast<uint4*>(dst) = *reinterpret_cast<uint4*>(tmp);
  }
}
__device__ __forceinline__ float clS(float v){ return fminf(30.f, fmaxf(-30.f, v)); }
__device__ __forceinline__ float clH(float v){ return fminf(1e4f, fmaxf(-1e4f, v)); }
__device__ __forceinline__ int binOf(float v, float lo, float inv){
  int c = (int)((v - lo) * inv);
  c = c < 0 ? 0 : c;
  c = c > NBINS - 1 ? NBINS - 1 : c;
  return c;
}
__device__ __forceinline__ int rdmask(const u8* m, int mode, int idx){
  return mode ? (m[idx] != 0) : (((const int*)m)[idx] != 0);
}

__global__ __launch_bounds__(1024) void k0_detect(const u8* __restrict__ mask,
                                                  const void* x, const void* prior,
                                                  const void* Wlin, const void* wh,
                                                  const void* asr, const void* ads,
                                                  int* __restrict__ flags,
                                                  float* __restrict__ colsum){
  __shared__ int c[8];
  const int t = threadIdx.x;
  for (int i = t; i < B_ * H_ * O_; i += 1024) colsum[i] = 0.f;
  if (t < 8) c[t] = 0;
  __syncthreads();
  int local = 0;
  for (int i = t; i < B_ * N1; i += 1024)
    if ((i & 3) && mask[i]) local = 1;
  if (local) atomicOr(&c[0], 1);
  const void* ptrs[6] = {x, prior, Wlin, wh, asr, ads};
  const int   lens[6] = {4096, 512, 4096, 4096, 512, 512};
  for (int k = 0; k < 6; k++){
    const u16* p = (const u16*)ptrs[k];
    int g = 0;
    for (int i = t; i < lens[k]; i += 1024){
      int e = (p[i] >> 7) & 0xFF;
      if (e >= 0xC0) g++;
    }
    if (g) atomicAdd(&c[k + 1], g);
  }
  __syncthreads();
  if (t == 0) flags[0] = c[0];
  else if (t <= 6) flags[t] = (c[t] < 4) ? 1 : 0;
}

__global__ __launch_bounds__(256) void ktr(const void* __restrict__ w_head,
                                           const int* __restrict__ flags,
                                           u16* __restrict__ wT){
  const int fw = flags[4];
  const int idx = blockIdx.x * 256 + threadIdx.x;
  const int h = idx >> 14, rem = idx & 16383, p = rem >> 7, o = rem & 127;
  wT[idx] = f2bf(ldv(w_head, fw, ((size_t)h * O_ + o) * O_ + p));
}

__global__ __launch_bounds__(256) void k1_hp(const void* __restrict__ x,
                                             const void* __restrict__ prior,
                                             const void* __restrict__ Wlin,
                                             const int* __restrict__ flags,
                                             u16* __restrict__ hpb){
  __shared__ __align__(16) u16 xs[32 * XS_STR];
  __shared__ __align__(16) u16 wl[128 * XS_STR];
  const int fx = flags[1], fpf = flags[2], fw = flags[3];
  const int tile = blockIdx.x & 63;
  const int b    = blockIdx.x >> 6;
  const int n0   = tile * 32;
  const int t = threadIdx.x;
  const int w = t >> 6, lane = t & 63, m16 = lane & 15, q = lane >> 4;
  const int rbase = (w & 1) * 16;
  const int cbase = (w >> 1) * 64;
  f32x4 acc[4];
#pragma unroll
  for (int nt = 0; nt < 4; nt++) acc[nt] = (f32x4){0.f, 0.f, 0.f, 0.f};
  for (int kt = 0; kt < I_; kt += 64){
    if (kt) __syncthreads();
    {
      const int row = t >> 3, ch = t & 7;
      const int n = n0 + row;
      if (n < N_) st8bf(&xs[row * XS_STR + ch * 8], x, fx, ((size_t)b * N_ + n) * I_ + kt + ch * 8);
      else { uint4 z = make_uint4(0,0,0,0); *reinterpret_cast<uint4*>(&xs[row * XS_STR + ch * 8]) = z; }
    }
#pragma unroll
    for (int it = 0; it < 4; it++){
      const int slot = t + it * 256, row = slot >> 3, ch = slot & 7;
      st8bf(&wl[row * XS_STR + ch * 8], Wlin, fw, (size_t)row * I_ + kt + ch * 8);
    }
    __syncthreads();
#pragma unroll
    for (int ks = 0; ks < 2; ks++){
      const int k0 = ks * 32 + q * 8;
      const bf16x8 af = *reinterpret_cast<const bf16x8*>(&xs[(rbase + m16) * XS_STR + k0]);
#pragma unroll
      for (int nt = 0; nt < 4; nt++){
        const bf16x8 bfr = *reinterpret_cast<const bf16x8*>(&wl[(cbase + nt * 16 + m16) * XS_STR + k0]);
        acc[nt] = MFMA16(af, bfr, acc[nt]);
      }
    }
  }
#pragma unroll
  for (int nt = 0; nt < 4; nt++){
#pragma unroll
    for (int r = 0; r < 4; r++){
      const int n = n0 + rbase + q * 4 + r;
      const int col = cbase + nt * 16 + m16;
      const float v = (n == N_) ? ldv(prior, fpf, b * O_ + col) : acc[nt][r];
      hpb[((size_t)b * N1 + n) * O_ + col] = f2bf(v);
    }
  }
}

__global__ __launch_bounds__(256) void k2_heads(const u16* __restrict__ hpb,
                                                const u16* __restrict__ wT,
                                                const void* __restrict__ a_src,
                                                const void* __restrict__ a_dst,
                                                const int* __restrict__ flags,
                                                float* __restrict__ hph,
                                                float* __restrict__ s_src,
                                                float* __restrict__ s_dst,
                                                float* __restrict__ colsum){
  __shared__ __align__(16) u16 hsb[64 * HS_STR];
  __shared__ __align__(16) u16 wtb[128 * HS_STR];
  __shared__ float colacc[O_];
  const int fas = flags[5], fad = flags[6];
  const int tile = blockIdx.x & 31;
  const int h    = (blockIdx.x >> 5) & 3;
  const int b    = blockIdx.x >> 7;
  const int bh   = b * H_ + h;
  const int n0   = tile * 64;
  const int t = threadIdx.x;
  const int w = t >> 6, lane = t & 63, m16 = lane & 15, q = lane >> 4;
  if (t < O_) colacc[t] = 0.f;
#pragma unroll
  for (int it = 0; it < 4; it++){
    const int slot = t + it * 256, row = slot >> 4, ch = slot & 15;
    *reinterpret_cast<uint4*>(&hsb[row * HS_STR + ch * 8]) =
      *reinterpret_cast<const uint4*>(&hpb[((size_t)b * N1 + n0 + row) * O_ + ch * 8]);
  }
#pragma unroll
  for (int it = 0; it < 8; it++){
    const int slot = t + it * 256, row = slot >> 4, ch = slot & 15;
    *reinterpret_cast<uint4*>(&wtb[row * HS_STR + ch * 8]) =
      *reinterpret_cast<const uint4*>(&wT[((size_t)h * O_ + row) * O_ + ch * 8]);
  }
  __syncthreads();
  f32x4 acc[8];
#pragma unroll
  for (int nt = 0; nt < 8; nt++) acc[nt] = (f32x4){0.f, 0.f, 0.f, 0.f};
#pragma unroll
  for (int ks = 0; ks < 4; ks++){
    const int k0 = ks * 32 + q * 8;
    const bf16x8 af = *reinterpret_cast<const bf16x8*>(&hsb[(w * 16 + m16) * HS_STR + k0]);
#pragma unroll
    for (int nt = 0; nt < 8; nt++){
      const bf16x8 bfr = *reinterpret_cast<const bf16x8*>(&wtb[(nt * 16 + m16) * HS_STR + k0]);
      acc[nt] = MFMA16(af, bfr, acc[nt]);
    }
  }
  float ps[4] = {0.f, 0.f, 0.f, 0.f}, pd[4] = {0.f, 0.f, 0.f, 0.f};
#pragma unroll
  for (int nt = 0; nt < 8; nt++){
    const int col = nt * 16 + m16;
    const float asv = ldv(a_src, fas, h * O_ + col);
    const float adv = ldv(a_dst, fad, h * O_ + col);
    float colpart = 0.f;
#pragma unroll
    for (int r = 0; r < 4; r++){
      const float v = clH(acc[nt][r]);
      hph[((size_t)bh * N1 + n0 + w * 16 + q * 4 + r) * O_ + col] = v;
      colpart += v;
      const float tv = tanhf(v);
      ps[r] += tv * asv;
      pd[r] += tv * adv;
    }
    atomicAdd(&colacc[col], colpart);
  }
#pragma unroll
  for (int r = 0; r < 4; r++){
#pragma unroll
    for (int m = 8; m > 0; m >>= 1){
      ps[r] += __shfl_xor(ps[r], m);
      pd[r] += __shfl_xor(pd[r], m);
    }
    if (m16 == 0){
      const int n = n0 + w * 16 + q * 4 + r;
      s_src[(size_t)bh * N1 + n] = ps[r];
      s_dst[(size_t)bh * N1 + n] = pd[r];
    }
  }
  __syncthreads();
  if (t < O_) atomicAdd(&colsum[bh * O_ + t], colacc[t]);
}

// ---- K3a: range (fused, was k2b) + counting sort of unmasked j by bin ----
__global__ __launch_bounds__(256) void k3a_bucket(const float* __restrict__ s_dst,
                                                  const u8* __restrict__ mask,
                                                  const int* __restrict__ flags,
                                                  float* __restrict__ sdlo,
                                                  float* __restrict__ sdinv,
                                                  int* __restrict__ binStart,
                                                  int* __restrict__ order){
  __shared__ float smn[4], smx[4];
  __shared__ float sli[2];
  __shared__ int cnt[NBINS];
  __shared__ int part[256];
  __shared__ int offs[256 + 1];
  const int bh = blockIdx.x, b = bh / H_, t = threadIdx.x;
  const int md = flags[0];
  float mn = 3e38f, mx = -3e38f;
  for (int j = t; j < N1; j += 256){
    if (!rdmask(mask, md, b * N1 + j)){
      float v = clS(s_dst[(size_t)bh * N1 + j]);
      mn = fminf(mn, v); mx = fmaxf(mx, v);
    }
  }
#pragma unroll
  for (int sft = 32; sft > 0; sft >>= 1){
    mn = fminf(mn, __shfl_down(mn, sft));
    mx = fmaxf(mx, __shfl_down(mx, sft));
  }
  if ((t & 63) == 0){ smn[t >> 6] = mn; smx[t >> 6] = mx; }
  __syncthreads();
  if (t == 0){
    mn = fminf(fminf(smn[0], smn[1]), fminf(smn[2], smn[3]));
    mx = fmaxf(fmaxf(smx[0], smx[1]), fmaxf(smx[2], smx[3]));
    float range = mx - mn;
    if (!(range > 1e-30f)) range = 1.f;
    const float inv = (float)NBINS / range;
    sdlo[bh]  = mn;
    sdinv[bh] = inv;
    sli[0] = mn; sli[1] = inv;
  }
  __syncthreads();
  const float lo = sli[0], inv = sli[1];
  cnt[t] = 0;
  __syncthreads();
  for (int j = t; j < N1; j += 256){
    if (!rdmask(mask, md, b * N1 + j))
      atomicAdd(&cnt[binOf(clS(s_dst[(size_t)bh * N1 + j]), lo, inv)], 1);
  }
  __syncthreads();
  const int mysum = cnt[t];
  part[t] = mysum;
  __syncthreads();
  for (int off = 1; off < 256; off <<= 1){
    int v = (t >= off) ? part[t - off] : 0;
    __syncthreads();
    part[t] += v;
    __syncthreads();
  }
  const int excl = part[t] - mysum;
  offs[t] = excl;
  binStart[bh * (NBINS + 1) + t] = excl;
  if (t == 255) binStart[bh * (NBINS + 1) + NBINS] = part[255];
  __syncthreads();
  for (int j = t; j < N1; j += 256){
    if (!rdmask(mask, md, b * N1 + j)){
      int bin = binOf(clS(s_dst[(size_t)bh * N1 + j]), lo, inv);
      int pos = atomicAdd(&offs[bin], 1);
      order[(size_t)bh * N1 + pos] = j;
    }
  }
}

__global__ __launch_bounds__(192) void k3b_binsum(const float* __restrict__ hph,
                                                  const float* __restrict__ s_dst,
                                                  const int* __restrict__ binStart,
                                                  const int* __restrict__ order,
                                                  float* __restrict__ binPos,
                                                  float* __restrict__ binNeg){
  __shared__ int jls[64];
  __shared__ float fpl[64], fnl[64];
  const int gb = blockIdx.x;
  const int bh = gb / NBINS, bin = gb % NBINS;
  const int t = threadIdx.x;
  const int s = binStart[bh * (NBINS + 1) + bin];
  const int e = binStart[bh * (NBINS + 1) + bin + 1];
  float ap = 0.f, an = 0.f;
  for (int mb = s; mb < e; mb += 64){
    const int cn = min(64, e - mb);
    if (t < cn){
      const int j = order[(size_t)bh * N1 + mb + t];
      const float sdj = clS(s_dst[(size_t)bh * N1 + j]);
      jls[t] = j;
      fpl[t] = __expf(sdj);
      fnl[t] = __expf(SLOPEC * sdj);
    }
    __syncthreads();
    for (int m = 0; m < cn; m++){
      const float v = (t < O_) ? hph[((size_t)bh * N1 + jls[m]) * O_ + t] : 1.f;
      ap += fpl[m] * v;
      an += fnl[m] * v;
    }
    __syncthreads();
  }
  if (t <= O_){
    const size_t basei = ((size_t)bh * NBINS + bin) * STR;
    binPos[basei + t] = ap;
    binNeg[basei + t] = an;
  }
}

__global__ __launch_bounds__(256) void k3c1(const float* __restrict__ binPos,
                                            const float* __restrict__ binNeg,
                                            float* __restrict__ chunkSum){
  const int idx = blockIdx.x * 256 + threadIdx.x;
  if (idx >= 2 * 16 * 4 * 129) return;
  const int ch = idx % 129;
  int rest = idx / 129;
  const int chunk = rest & 3;
  rest >>= 2;
  const int bh = rest & 15;
  const int arr = rest >> 4;
  const float* src = arr ? binPos : binNeg;
  float s = 0.f;
  const size_t base = ((size_t)bh * NBINS + chunk * 64) * STR + ch;
  for (int r = 0; r < 64; r++) s += src[base + (size_t)r * STR];
  chunkSum[(((size_t)arr * 16 + bh) * 4 + chunk) * STR + ch] = s;
}

__global__ __launch_bounds__(256) void k3c2(const float* __restrict__ binPos,
                                            const float* __restrict__ binNeg,
                                            const float* __restrict__ chunkSum,
                                            float* __restrict__ sufPos,
                                            float* __restrict__ preNeg){
  const int idx = blockIdx.x * 256 + threadIdx.x;
  if (idx >= 2 * 16 * 4 * 129) return;
  const int ch = idx % 129;
  int rest = idx / 129;
  const int chunk = rest & 3;
  rest >>= 2;
  const int bh = rest & 15;
  const int arr = rest >> 4;
  if (arr == 0){
    float acc = 0.f;
    for (int cc = 0; cc < chunk; cc++)
      acc += chunkSum[(((size_t)bh) * 4 + cc) * STR + ch];
    for (int rr = 0; rr < 64; rr++){
      const int r = chunk * 64 + rr;
      preNeg[((size_t)bh * (NBINS + 1) + r) * STR + ch] = acc;
      acc += binNeg[((size_t)bh * NBINS + r) * STR + ch];
    }
    if (chunk == 3) preNeg[((size_t)bh * (NBINS + 1) + NBINS) * STR + ch] = acc;
  } else {
    float acc = 0.f;
    for (int cc = chunk + 1; cc < 4; cc++)
      acc += chunkSum[(((size_t)16 + bh) * 4 + cc) * STR + ch];
    for (int rr = 63; rr >= 0; rr--){
      const int r = chunk * 64 + rr;
      acc += binPos[((size_t)bh * NBINS + r) * STR + ch];
      sufPos[((size_t)bh * (NBINS + 1) + r) * STR + ch] = acc;
    }
    if (chunk == 3) sufPos[((size_t)bh * (NBINS + 1) + NBINS) * STR + ch] = 0.f;
  }
}

// ---- K3d: 1 row/block, 512 thr (4 heads x 128 ch); wave-shuffle members ----
__global__ __launch_bounds__(512) void k3d_out(const float* __restrict__ hph,
                                               const float* __restrict__ s_src,
                                               const float* __restrict__ s_dst,
                                               const u8* __restrict__ mask,
                                               const int* __restrict__ flags,
                                               const float* __restrict__ sdlo,
                                               const float* __restrict__ sdinv,
                                               const int* __restrict__ binStart,
                                               const int* __restrict__ order,
                                               const float* __restrict__ sufPos,
                                               const float* __restrict__ preNeg,
                                               const float* __restrict__ colsum,
                                               const void* __restrict__ bias,
                                               void* __restrict__ outp){
  __shared__ float part[4 * STR];
  const int blk = blockIdx.x;
  const int b = blk >> 11, i = blk & (N1 - 1);
  const int t = threadIdx.x;
  const int h = t >> 7, o = t & 127;
  const int lane = t & 63;
  const int md = flags[0], fo = flags[1];
  const int bh = b * H_ + h;
  const int U = binStart[bh * (NBINS + 1) + NBINS];
  const bool mrow = rdmask(mask, md, b * N1 + i) != 0;
  float contrib;
  if (mrow || U == 0){
    contrib = colsum[bh * O_ + o] * (1.f / N1);
  } else {
    const float si = clS(s_src[(size_t)bh * N1 + i]);
    const float tthr = -si;
    const int c = binOf(tthr, sdlo[bh], sdinv[bh]);
    const size_t rowp = ((size_t)bh * (NBINS + 1) + c + 1) * STR;
    const size_t rown = ((size_t)bh * (NBINS + 1) + c) * STR;
    float posV = sufPos[rowp + o], posS = sufPos[rowp + O_];
    float negV = preNeg[rown + o], negS = preNeg[rown + O_];
    const int s0 = binStart[bh * (NBINS + 1) + c];
    const int e0 = binStart[bh * (NBINS + 1) + c + 1];
    for (int mb = s0; mb < e0; mb += 64){
      const int cn = min(64, e0 - mb);
      int jm = 0; float sdm = 0.f, fpm = 0.f, fnm = 0.f;
      if (lane < cn){
        jm = order[(size_t)bh * N1 + mb + lane];
        sdm = clS(s_dst[(size_t)bh * N1 + jm]);
        fpm = __expf(sdm);
        fnm = __expf(SLOPEC * sdm);
      }
      int m = 0;
      for (; m + 3 < cn; m += 4){
        const int j0 = __shfl(jm, m),     j1 = __shfl(jm, m + 1);
        const int j2 = __shfl(jm, m + 2), j3 = __shfl(jm, m + 3);
        const float hv0 = hph[((size_t)bh * N1 + j0) * O_ + o];
        const float hv1 = hph[((size_t)bh * N1 + j1) * O_ + o];
        const float hv2 = hph[((size_t)bh * N1 + j2) * O_ + o];
        const float hv3 = hph[((size_t)bh * N1 + j3) * O_ + o];
        const float sd0 = __shfl(sdm, m),     sd1 = __shfl(sdm, m + 1);
        const float sd2 = __shfl(sdm, m + 2), sd3 = __shfl(sdm, m + 3);
        const float fp0 = __shfl(fpm, m),     fp1 = __shfl(fpm, m + 1);
        const float fp2 = __shfl(fpm, m + 2), fp3 = __shfl(fpm, m + 3);
        const float fn0 = __shfl(fnm, m),     fn1 = __shfl(fnm, m + 1);
        const float fn2 = __shfl(fnm, m + 2), fn3 = __shfl(fnm, m + 3);
        if (sd0 >= tthr){ posV += fp0 * hv0; posS += fp0; } else { negV += fn0 * hv0; negS += fn0; }
        if (sd1 >= tthr){ posV += fp1 * hv1; posS += fp1; } else { negV += fn1 * hv1; negS += fn1; }
        if (sd2 >= tthr){ posV += fp2 * hv2; posS += fp2; } else { negV += fn2 * hv2; negS += fn2; }
        if (sd3 >= tthr){ posV += fp3 * hv3; posS += fp3; } else { negV += fn3 * hv3; negS += fn3; }
      }
      for (; m < cn; m++){
        const int j = __shfl(jm, m);
        const float sdj = __shfl(sdm, m);
        const float fp = __shfl(fpm, m);
        const float fn = __shfl(fnm, m);
        const float hv = hph[((size_t)bh * N1 + j) * O_ + o];
        if (sdj >= tthr){ posV += fp * hv; posS += fp; }
        else            { negV += fn * hv; negS += fn; }
      }
    }
    const float esi = __expf(si), esi2 = __expf(SLOPEC * si);
    const float den = fmaxf(esi * posS + esi2 * negS, 1e-35f);
    contrib = (esi * posV + esi2 * negV) / den;
  }
  part[h * STR + o] = contrib;
  __syncthreads();
  if (t < O_){
    const float sum = part[0 * STR + t] + part[1 * STR + t] + part[2 * STR + t] + part[3 * STR + t];
    const float v = 0.25f * sum + ldv(bias, fo, t);
    const size_t oidx = ((size_t)b * N1 + i) * O_ + t;
    if (fo) ((u16*)outp)[oidx] = f2bf(v);
    else    ((float*)outp)[oidx] = v;
  }
}

extern "C" void kernel_launch(void* const* d_in, const int* in_sizes, int n_in,
                              void* d_out, int out_size, void* d_ws, size_t ws_size,
                              hipStream_t stream){
  const void* x      = d_in[0];
  const void* prior  = d_in[1];
  const u8*   mask   = (const u8*)d_in[2];
  const void* Wlin   = d_in[3];
  const void* w_head = d_in[4];
  const void* a_src  = d_in[5];
  const void* a_dst  = d_in[6];
  const void* bias   = d_in[7];

  char* basep = (char*)d_ws;
  size_t off = 0;
  auto alloc = [&](size_t bytes) -> void* {
    off = (off + 255) & ~(size_t)255;
    void* p = basep + off;
    off += bytes;
    return p;
  };
  int*   flags    = (int*)alloc(32);
  u16*   wT       = (u16*)alloc((size_t)H_ * O_ * O_ * 2);
  u16*   hpb      = (u16*)alloc((size_t)B_ * N1 * O_ * 2);
  float* hph      = (float*)alloc((size_t)B_ * H_ * N1 * O_ * 4);
  float* s_src    = (float*)alloc((size_t)B_ * H_ * N1 * 4);
  float* s_dst    = (float*)alloc((size_t)B_ * H_ * N1 * 4);
  float* sdlo     = (float*)alloc(B_ * H_ * 4);
  float* sdinv    = (float*)alloc(B_ * H_ * 4);
  float* colsum   = (float*)alloc((size_t)B_ * H_ * O_ * 4);
  int*   binStart = (int*)alloc((size_t)B_ * H_ * (NBINS + 1) * 4);
  int*   order    = (int*)alloc((size_t)B_ * H_ * N1 * 4);
  float* binPos   = (float*)alloc((size_t)B_ * H_ * NBINS * STR * 4);
  float* binNeg   = (float*)alloc((size_t)B_ * H_ * NBINS * STR * 4);
  float* sufPos   = (float*)alloc((size_t)B_ * H_ * (NBINS + 1) * STR * 4);
  float* preNeg   = (float*)alloc((size_t)B_ * H_ * (NBINS + 1) * STR * 4);
  float* chunkSum = (float*)alloc((size_t)2 * 16 * 4 * STR * 4);
  (void)in_sizes; (void)n_in; (void)out_size; (void)ws_size;

  const int scanN = 2 * 16 * 4 * 129;
  hipLaunchKernelGGL(k0_detect,  dim3(1),                   dim3(1024), 0, stream, mask, x, prior, Wlin, w_head, a_src, a_dst, flags, colsum);
  hipLaunchKernelGGL(ktr,        dim3(256),                 dim3(256), 0, stream, w_head, flags, wT);
  hipLaunchKernelGGL(k1_hp,      dim3(B_ * 64),             dim3(256), 0, stream, x, prior, Wlin, flags, hpb);
  hipLaunchKernelGGL(k2_heads,   dim3(B_ * H_ * 32),        dim3(256), 0, stream, hpb, wT, a_src, a_dst, flags, hph, s_src, s_dst, colsum);
  hipLaunchKernelGGL(k3a_bucket, dim3(B_ * H_),             dim3(256), 0, stream, s_dst, mask, flags, sdlo, sdinv, binStart, order);
  hipLaunchKernelGGL(k3b_binsum, dim3(B_ * H_ * NBINS),     dim3(192), 0, stream, hph, s_dst, binStart, order, binPos, binNeg);
  hipLaunchKernelGGL(k3c1,       dim3((scanN + 255) / 256), dim3(256), 0, stream, binPos, binNeg, chunkSum);
  hipLaunchKernelGGL(k3c2,       dim3((scanN + 255) / 256), dim3(256), 0, stream, binPos, binNeg, chunkSum, sufPos, preNeg);
  hipLaunchKernelGGL(k3d_out,    dim3(B_ * N1),             dim3(512), 0, stream, hph, s_src, s_dst, mask, flags, sdlo, sdinv, binStart, order, sufPos, preNeg, colsum, bias, d_out);
}